// Round 1
// baseline (117.016 us; speedup 1.0000x reference)
//
#include <hip/hip_runtime.h>
#include <stdint.h>

#define NN   4096
#define KK   32
#define HID  128
#define BLK  256
#define WPB  4                 // waves per block = nodes per block
#define GRID (NN / WPB)
#define CAP  128

typedef unsigned short bf16_t;
typedef __attribute__((ext_vector_type(8))) short bf16x8;
typedef __attribute__((ext_vector_type(4))) float f32x4;

#define FINF __uint_as_float(0x7f800000u)

// single-instruction packed f32->bf16 (RTNE), replaces manual bit-twiddle pairs
__device__ __forceinline__ uint32_t pk2bf(float lo, float hi) {
    uint32_t r;
    asm("v_cvt_pk_bf16_f32 %0, %1, %2" : "=v"(r) : "v"(lo), "v"(hi));
    return r;
}
__device__ __forceinline__ float siluf(float x) {
    return x / (1.0f + __expf(-x));
}

// 4 distances for j = g*256 + 4*lane + c (exact fp32 chain; self -> inf)
__device__ __forceinline__ void dist4(const float4* __restrict__ p4, int g, int lane,
                                      float px, float py, float pz, int iself,
                                      float d[4]) {
    float4 f0 = p4[g*192 + 3*lane];
    float4 f1 = p4[g*192 + 3*lane + 1];
    float4 f2 = p4[g*192 + 3*lane + 2];
    float jx[4] = {f0.x, f0.w, f1.z, f2.y};
    float jy[4] = {f0.y, f1.x, f1.w, f2.z};
    float jz[4] = {f0.z, f1.y, f2.x, f2.w};
    #pragma unroll
    for (int c = 0; c < 4; ++c) {
        int j = g*256 + 4*lane + c;
        float dx = px - jx[c], dy = py - jy[c], dz = pz - jz[c];
        float dd = __fadd_rn(__fadd_rn(__fmul_rn(dx,dx), __fmul_rn(dy,dy)),
                             __fmul_rn(dz,dz));
        d[c] = (j == iself) ? FINF : dd;
    }
}

// ---- prepack: W2 fp32 -> bf16 in MFMA B-fragment order (frag f = NT*4+kk) ----
__global__ __launch_bounds__(256) void prepack_w2(
    const float* __restrict__ W2, uint4* __restrict__ w2b)
{
    int c  = blockIdx.x * 256 + threadIdx.x;
    int f  = c >> 6, ln = c & 63;
    int NT = f >> 2, kk = f & 3;
    int row = NT*16 + (ln & 15);
    int k0  = kk*32 + (ln >> 4) * 8;
    const float* s = W2 + row * HID + k0;
    float4 lo = *(const float4*)s;
    float4 hi = *(const float4*)(s + 4);
    uint4 pk;
    pk.x = pk2bf(lo.x, lo.y);
    pk.y = pk2bf(lo.z, lo.w);
    pk.z = pk2bf(hi.x, hi.y);
    pk.w = pk2bf(hi.z, hi.w);
    w2b[c] = pk;
}

template<bool WS>
struct __align__(16) Sm {
    // per-wave 8 KB region: dbf (selection phase) then h1 (MLP phase) — same-wave
    // program order makes the union safe with no barrier.
    union __align__(16) U {
        ushort dbf[NN];                 // top-16 distance bits per j
        ushort h1[KK * HID];            // MLP A-operand (32 edges x 128, swizzled)
    } uw[WPB];                          // 32 KB total
    uint32_t cand[WPB][CAP];            // 2 KB : per-wave (d16<<16)|j keys
    float    rads[WPB][KK];             // per-wave edge radial
    float    sedge[WPB][KK];            // per-wave edge scalar
    int      recvs[WPB][KK];            // per-wave neighbor ids
    uint32_t w2l[WS ? 4 : HID * 64];    // W2 LDS staging only in no-workspace path
};

template<bool WS>
__global__ __launch_bounds__(BLK) void egnn_main(
    const float* __restrict__ pos, const float* __restrict__ tptr,
    const float* __restrict__ W1,  const float* __restrict__ b1,
    const float* __restrict__ g1,  const float* __restrict__ W2,
    const float* __restrict__ b2,  const float* __restrict__ g2,
    const float* __restrict__ W3,  const float* __restrict__ b3,
    const uint4* __restrict__ w2b, float* __restrict__ out)
{
    __shared__ Sm<WS> sm;
    const int tid  = threadIdx.x;
    const int lane = tid & 63;
    const int wid  = tid >> 6;                  // 0..3: this wave / its node
    const int i    = blockIdx.x * WPB + wid;    // node handled by this wave
    const int l15  = lane & 15, lq = lane >> 4;

    const float ts  = tptr[0];
    const float b3s = b3[0];

    // closed-form RMS coefficients (wave-reduced -> lane-uniform):
    // sum_n (rad*a_n + c_n)^2 = rad^2*A2 + 2*rad*AC + C2
    float A2, AC, C2;
    {
        const float4 w1v = ((const float4*)W1)[lane];     // rows 2l,2l+1
        const float2 b1v = ((const float2*)b1)[lane];
        float t0 = ts * w1v.y + b1v.x;
        float t1 = ts * w1v.w + b1v.y;
        A2 = w1v.x*w1v.x + w1v.z*w1v.z;
        AC = w1v.x*t0    + w1v.z*t1;
        C2 = t0*t0       + t1*t1;
        #pragma unroll
        for (int m = 32; m >= 1; m >>= 1) {
            A2 += __shfl_xor(A2, m, 64);
            AC += __shfl_xor(AC, m, 64);
            C2 += __shfl_xor(C2, m, 64);
        }
    }

    if constexpr (!WS) {
        // fallback: stage W2 into LDS (bf16, 16B chunks XOR-swizzled by row&15)
        for (int idx = tid; idx < HID * 16; idx += BLK) {
            int row = idx >> 4, c = idx & 15;
            const float* src = W2 + row * HID + c * 8;
            float4 lo = *(const float4*)src;
            float4 hi = *(const float4*)(src + 4);
            uint4 pk;
            pk.x = pk2bf(lo.x, lo.y);
            pk.y = pk2bf(lo.z, lo.w);
            pk.z = pk2bf(hi.x, hi.y);
            pk.w = pk2bf(hi.z, hi.w);
            *((uint4*)&sm.w2l[row * 64 + 4 * (c ^ (row & 15))]) = pk;
        }
        __syncthreads();      // only barrier, fallback path only
    }

    const float px = pos[3*i], py = pos[3*i+1], pz = pos[3*i+2];
    const float4* p4 = (const float4*)pos;

    // ---- pass 1: distances ONCE; d16 to per-wave LDS; per-lane sample min ----
    float mind = FINF;
    {
        ushort* dbf = sm.uw[wid].dbf;
        #pragma unroll 4
        for (int g = 0; g < 16; ++g) {
            float d[4];
            dist4(p4, g, lane, px, py, pz, i, d);
            uint32_t lo = (__float_as_uint(d[0]) >> 16) | (__float_as_uint(d[1]) & 0xffff0000u);
            uint32_t hi = (__float_as_uint(d[2]) >> 16) | (__float_as_uint(d[3]) & 0xffff0000u);
            *((uint2*)&dbf[g*256 + 4*lane]) = make_uint2(lo, hi);
            mind = fminf(fminf(fminf(mind, d[0]), fminf(d[1], d[2])), d[3]);
        }
    }
    const uint32_t m16 = __float_as_uint(mind) >> 16;

    // ---- v = 32nd smallest sample-min (16-bit radix search via ballot) ----
    // >=32 sample-mins at DISTINCT j (lanes own disjoint j sets, self excluded)
    // are <= v  =>  the 32 smallest (d16,j) keys all have d16 <= v.
    uint32_t v = 0;
    #pragma unroll
    for (int b = 15; b >= 0; --b) {
        uint32_t t = v | (1u << b);
        int nl = (int)__popcll(__ballot(m16 < t));
        if (nl < KK) v = t;
    }

    // ---- compaction v2: per-lane candidate count -> one wave exclusive scan ->
    //      per-lane sequential slot writes. Replaces the 64 serial ballot steps;
    //      slot ORDER is irrelevant (rank-select orders by key), only cnt and
    //      distinct-slot coverage matter. Reads are batched, independent. ----
    uint32_t cnt = 0;
    {
        const ushort* dbf = sm.uw[wid].dbf;
        uint32_t myc = 0;
        #pragma unroll 4
        for (int g = 0; g < 16; ++g) {
            uint2 w = *((const uint2*)&dbf[g*256 + 4*lane]);
            myc += (uint32_t)((w.x & 0xffffu) <= v);
            myc += (uint32_t)((w.x >> 16)     <= v);
            myc += (uint32_t)((w.y & 0xffffu) <= v);
            myc += (uint32_t)((w.y >> 16)     <= v);
        }
        // exclusive scan across the wave (6 shfl_up steps)
        uint32_t inc = myc;
        #pragma unroll
        for (int off = 1; off < 64; off <<= 1) {
            uint32_t y = __shfl_up(inc, off, 64);
            if (lane >= off) inc += y;
        }
        uint32_t slot = inc - myc;
        cnt = (uint32_t)__shfl((int)inc, 63, 64);
        // second pass: emit keys at per-lane consecutive slots
        if (myc) {
            #pragma unroll 4
            for (int g = 0; g < 16; ++g) {
                uint2 w = *((const uint2*)&dbf[g*256 + 4*lane]);
                uint32_t d16v[4] = {w.x & 0xffffu, w.x >> 16, w.y & 0xffffu, w.y >> 16};
                #pragma unroll
                for (int c = 0; c < 4; ++c) {
                    if (d16v[c] <= v) {
                        if (slot < CAP)
                            sm.cand[wid][slot] = (d16v[c] << 16)
                                               | (unsigned)(g*256 + 4*lane + c);
                        slot++;
                    }
                }
            }
        }
    }
    const int cntv = (int)cnt;

    if (cntv <= CAP) {
        // ---- rank-select: lane ranks cand[lane] and cand[64+lane] ----
        // 16-wide batches: 4 consecutive ds_read_b128 issued together so LDS
        // latency is amortized 4-deep (was 1 serial b128 per 4 keys).
        #pragma unroll
        for (int h = 0; h < 2; ++h) {
            int idx = h*64 + lane;
            if (idx < cntv) {
                uint32_t km = sm.cand[wid][idx];
                int rank = 0;
                for (int q = 0; q < cntv; q += 16) {
                    const uint4* cp = (const uint4*)&sm.cand[wid][q];
                    uint4 u0 = cp[0];
                    uint4 u1 = cp[1];
                    uint4 u2 = cp[2];
                    uint4 u3 = cp[3];
                    rank += (q      < cntv && u0.x < km) ? 1 : 0;
                    rank += (q +  1 < cntv && u0.y < km) ? 1 : 0;
                    rank += (q +  2 < cntv && u0.z < km) ? 1 : 0;
                    rank += (q +  3 < cntv && u0.w < km) ? 1 : 0;
                    rank += (q +  4 < cntv && u1.x < km) ? 1 : 0;
                    rank += (q +  5 < cntv && u1.y < km) ? 1 : 0;
                    rank += (q +  6 < cntv && u1.z < km) ? 1 : 0;
                    rank += (q +  7 < cntv && u1.w < km) ? 1 : 0;
                    rank += (q +  8 < cntv && u2.x < km) ? 1 : 0;
                    rank += (q +  9 < cntv && u2.y < km) ? 1 : 0;
                    rank += (q + 10 < cntv && u2.z < km) ? 1 : 0;
                    rank += (q + 11 < cntv && u2.w < km) ? 1 : 0;
                    rank += (q + 12 < cntv && u3.x < km) ? 1 : 0;
                    rank += (q + 13 < cntv && u3.y < km) ? 1 : 0;
                    rank += (q + 14 < cntv && u3.z < km) ? 1 : 0;
                    rank += (q + 15 < cntv && u3.w < km) ? 1 : 0;
                }
                if (rank < KK) sm.recvs[wid][rank] = (int)(km & 0xFFFFu);
            }
        }
    } else {
        // ---- cold fallback (overflow; ~never): exact wave-local argmin x32,
        //      per-lane 64-bit exclusion mask for its own j's (recompute) ----
        unsigned long long locmask = 0ull;
        for (int it = 0; it < KK; ++it) {
            unsigned long long best = ~0ull;
            for (int g = 0; g < 16; ++g) {
                float d[4];
                dist4(p4, g, lane, px, py, pz, i, d);
                #pragma unroll
                for (int c = 0; c < 4; ++c) {
                    bool dead = ((locmask >> (g*4 + c)) & 1ull) != 0ull;
                    unsigned long long key = dead ? ~0ull
                        : ((((unsigned long long)__float_as_uint(d[c])) << 12)
                           | (unsigned)(g*256 + 4*lane + c));
                    best = best < key ? best : key;
                }
            }
            #pragma unroll
            for (int m = 32; m >= 1; m >>= 1) {
                unsigned long long o = __shfl_xor(best, m, 64);
                best = best < o ? best : o;
            }
            int j = (int)(best & 0xfffull);
            if (lane == 0) sm.recvs[wid][it] = j;
            if (((j >> 2) & 63) == lane)
                locmask |= 1ull << ((j >> 8) * 4 + (j & 3));
        }
    }

    // ---- edge gather: lane e < 32 holds neighbor e's geometry ----
    float cdx = 0.f, cdy = 0.f, cdz = 0.f;
    if (lane < KK) {
        int r = sm.recvs[wid][lane];
        cdx = px - pos[3*r];
        cdy = py - pos[3*r+1];
        cdz = pz - pos[3*r+2];
        float rad = __fadd_rn(__fadd_rn(__fmul_rn(cdx,cdx), __fmul_rn(cdy,cdy)),
                              __fmul_rn(cdz,cdz));
        sm.rads[wid][lane] = rad;
    }

    // ---- layer 1: all 32 edges of this node; lane = ch*4 + epr ----
    // h1 overwrites dbf (same union region) — all dbf reads completed above in
    // this wave's program order.
    {
        const int ch = lane >> 2, epr = lane & 3;
        float4 wA = ((const float4*)W1)[ch*4    ];
        float4 wB = ((const float4*)W1)[ch*4 + 1];
        float4 wC = ((const float4*)W1)[ch*4 + 2];
        float4 wD = ((const float4*)W1)[ch*4 + 3];
        float4 bA = ((const float4*)b1)[ch*2], bB = ((const float4*)b1)[ch*2 + 1];
        float4 gA = ((const float4*)g1)[ch*2], gB = ((const float4*)g1)[ch*2 + 1];
        float av[8] = {wA.x, wA.z, wB.x, wB.z, wC.x, wC.z, wD.x, wD.z};
        float cv[8] = {ts*wA.y + bA.x, ts*wA.w + bA.y, ts*wB.y + bA.z, ts*wB.w + bA.w,
                       ts*wC.y + bB.x, ts*wC.w + bB.y, ts*wD.y + bB.z, ts*wD.w + bB.w};
        float gv[8] = {gA.x, gA.y, gA.z, gA.w, gB.x, gB.y, gB.z, gB.w};
        uint4* h1q = (uint4*)&sm.uw[wid].h1[0];
        #pragma unroll
        for (int g = 0; g < 8; ++g) {
            int E = 4*g + epr;                    // 0..31
            float rad = sm.rads[wid][E];
            float sqv = rad*rad*A2 + 2.0f*rad*AC + C2;
            float rn  = rsqrtf(sqv * (1.0f/HID) + 1e-5f);
            uint32_t pk[4];
            #pragma unroll
            for (int p = 0; p < 4; ++p) {
                float va = siluf((rad*av[2*p]   + cv[2*p])   * rn * gv[2*p]);
                float vb = siluf((rad*av[2*p+1] + cv[2*p+1]) * rn * gv[2*p+1]);
                pk[p] = pk2bf(va, vb);
            }
            h1q[E*16 + (ch ^ (E & 15))] = uint4{pk[0], pk[1], pk[2], pk[3]};
        }
    }
    // no barrier: h1[wid] written and read only by this wave (DS program order)

    // ---- epilogue constants: n = nt*16 + l15 (shared by both m-tile passes) ----
    float g2v[8], w3v[8], b2v[8];
    #pragma unroll
    for (int nt = 0; nt < 8; ++nt) {
        int n = nt*16 + l15;
        g2v[nt] = g2[n]; w3v[nt] = W3[n]; b2v[nt] = b2[n];
    }

    // ---- layer 2 + epilogue: two m-tile passes (16 edges each), all 8 n-tiles ----
    const bf16x8* h1v = (const bf16x8*)&sm.uw[wid].h1[0];
    #pragma unroll
    for (int mt = 0; mt < 2; ++mt) {
        f32x4 acc[8];
        #pragma unroll
        for (int nt = 0; nt < 8; ++nt) acc[nt] = f32x4{0.f, 0.f, 0.f, 0.f};
        const int m = mt*16 + l15;
        if constexpr (WS) {
            const bf16x8* bv = (const bf16x8*)w2b;
            #pragma unroll
            for (int kk = 0; kk < 4; ++kk) {
                bf16x8 af = h1v[m*16 + ((kk*4 + lq) ^ l15)];
                #pragma unroll
                for (int nt = 0; nt < 8; ++nt)
                    acc[nt] = __builtin_amdgcn_mfma_f32_16x16x32_bf16(
                                  af, bv[(nt*4 + kk)*64 + lane], acc[nt], 0, 0, 0);
            }
        } else {
            const bf16x8* w2v = (const bf16x8*)sm.w2l;    // [128][16 chunks]
            #pragma unroll
            for (int kk = 0; kk < 4; ++kk) {
                const int q = (kk*4 + lq) ^ l15;
                bf16x8 af = h1v[m*16 + q];
                #pragma unroll
                for (int nt = 0; nt < 8; ++nt)
                    acc[nt] = __builtin_amdgcn_mfma_f32_16x16x32_bf16(
                                  af, w2v[(nt*16 + l15)*16 + q], acc[nt], 0, 0, 0);
            }
        }

        // RMS over all 128 neurons: in-lane sum over 8 nt + shfl over l15 bits
        float ss[4];
        #pragma unroll
        for (int r = 0; r < 4; ++r) {
            float t = 0.f;
            #pragma unroll
            for (int nt = 0; nt < 8; ++nt) {
                float zz = acc[nt][r] + b2v[nt];
                acc[nt][r] = zz;
                t += zz*zz;
            }
            ss[r] = t;
        }
        #pragma unroll
        for (int m2 = 1; m2 <= 8; m2 <<= 1) {
            #pragma unroll
            for (int r = 0; r < 4; ++r) ss[r] += __shfl_xor(ss[r], m2, 64);
        }
        float sp[4];
        #pragma unroll
        for (int r = 0; r < 4; ++r) {
            float rn = rsqrtf(ss[r] * (1.0f/HID) + 1e-5f);
            float t = 0.f;
            #pragma unroll
            for (int nt = 0; nt < 8; ++nt)
                t += siluf(acc[nt][r] * rn * g2v[nt]) * w3v[nt];
            sp[r] = t;
        }
        #pragma unroll
        for (int m2 = 1; m2 <= 8; m2 <<= 1) {
            #pragma unroll
            for (int r = 0; r < 4; ++r) sp[r] += __shfl_xor(sp[r], m2, 64);
        }
        if (l15 == 0) {
            #pragma unroll
            for (int r = 0; r < 4; ++r)
                sm.sedge[wid][mt*16 + lq*4 + r] = sp[r] + b3s;
        }
    }

    // ---- final: sum 32 edge messages (lane e holds cd of edge e) ----
    float mx = 0.f, my = 0.f, mz = 0.f;
    if (lane < KK) {
        float s = sm.sedge[wid][lane];
        mx = cdx * s; my = cdy * s; mz = cdz * s;
    }
    #pragma unroll
    for (int m = 32; m >= 1; m >>= 1) {
        mx += __shfl_xor(mx, m, 64);
        my += __shfl_xor(my, m, 64);
        mz += __shfl_xor(mz, m, 64);
    }
    if (lane == 0) {
        out[3*i    ] = px + mx * (1.0f/KK);
        out[3*i + 1] = py + my * (1.0f/KK);
        out[3*i + 2] = pz + mz * (1.0f/KK);
    }
}

extern "C" void kernel_launch(void* const* d_in, const int* in_sizes, int n_in,
                              void* d_out, int out_size, void* d_ws, size_t ws_size,
                              hipStream_t stream) {
    (void)in_sizes; (void)n_in; (void)out_size;
    const float* pos = (const float*)d_in[0];
    const float* t   = (const float*)d_in[1];
    const float* W1  = (const float*)d_in[2];
    const float* b1  = (const float*)d_in[3];
    const float* g1  = (const float*)d_in[4];
    const float* W2  = (const float*)d_in[5];
    const float* b2  = (const float*)d_in[6];
    const float* g2  = (const float*)d_in[7];
    const float* W3  = (const float*)d_in[8];
    const float* b3  = (const float*)d_in[9];
    float* out = (float*)d_out;

    if (d_ws != nullptr && ws_size >= 32768) {
        prepack_w2<<<8, 256, 0, stream>>>(W2, (uint4*)d_ws);
        egnn_main<true><<<GRID, BLK, 0, stream>>>(
            pos, t, W1, b1, g1, W2, b2, g2, W3, b3, (const uint4*)d_ws, out);
    } else {
        egnn_main<false><<<GRID, BLK, 0, stream>>>(
            pos, t, W1, b1, g1, W2, b2, g2, W3, b3, nullptr, out);
    }
}

// Round 2
// 109.307 us; speedup vs baseline: 1.0705x; 1.0705x over previous
//
#include <hip/hip_runtime.h>
#include <stdint.h>

#define NN   4096
#define KK   32
#define HID  128
#define BLK  256
#define WPB  4                 // waves per block = nodes per block
#define GRID (NN / WPB)
#define CAP  128

typedef unsigned short bf16_t;
typedef __attribute__((ext_vector_type(8))) short bf16x8;
typedef __attribute__((ext_vector_type(4))) float f32x4;

#define FINF __uint_as_float(0x7f800000u)

// single-instruction packed f32->bf16 (RTNE), replaces manual bit-twiddle pairs
__device__ __forceinline__ uint32_t pk2bf(float lo, float hi) {
    uint32_t r;
    asm("v_cvt_pk_bf16_f32 %0, %1, %2" : "=v"(r) : "v"(lo), "v"(hi));
    return r;
}
// raw v_rcp_f32 / v_rsq_f32 (1-ulp approx): avoids the ~10-instr IEEE div /
// refined-rsqrt expansions. Values feed bf16-rounded or tolerance-dominated
// paths, so 1 ulp is harmless.
__device__ __forceinline__ float fastrcp(float x) {
    float r; asm("v_rcp_f32 %0, %1" : "=v"(r) : "v"(x)); return r;
}
__device__ __forceinline__ float fastrsq(float x) {
    float r; asm("v_rsq_f32 %0, %1" : "=v"(r) : "v"(x)); return r;
}
__device__ __forceinline__ float siluf(float x) {
    return x * fastrcp(1.0f + __expf(-x));
}

// 4 distances for j = g*256 + 4*lane + c (exact fp32 chain; self handled by
// the caller — i is wave-uniform, so self-exclusion lives in one group only)
__device__ __forceinline__ void dist4(const float4* __restrict__ p4, int g, int lane,
                                      float px, float py, float pz,
                                      float d[4]) {
    float4 f0 = p4[g*192 + 3*lane];
    float4 f1 = p4[g*192 + 3*lane + 1];
    float4 f2 = p4[g*192 + 3*lane + 2];
    float jx[4] = {f0.x, f0.w, f1.z, f2.y};
    float jy[4] = {f0.y, f1.x, f1.w, f2.z};
    float jz[4] = {f0.z, f1.y, f2.x, f2.w};
    #pragma unroll
    for (int c = 0; c < 4; ++c) {
        float dx = px - jx[c], dy = py - jy[c], dz = pz - jz[c];
        d[c] = __fadd_rn(__fadd_rn(__fmul_rn(dx,dx), __fmul_rn(dy,dy)),
                         __fmul_rn(dz,dz));
    }
}

// ---- prepack: W2 fp32 -> bf16 in MFMA B-fragment order (frag f = NT*4+kk) ----
__global__ __launch_bounds__(256) void prepack_w2(
    const float* __restrict__ W2, uint4* __restrict__ w2b)
{
    int c  = blockIdx.x * 256 + threadIdx.x;
    int f  = c >> 6, ln = c & 63;
    int NT = f >> 2, kk = f & 3;
    int row = NT*16 + (ln & 15);
    int k0  = kk*32 + (ln >> 4) * 8;
    const float* s = W2 + row * HID + k0;
    float4 lo = *(const float4*)s;
    float4 hi = *(const float4*)(s + 4);
    uint4 pk;
    pk.x = pk2bf(lo.x, lo.y);
    pk.y = pk2bf(lo.z, lo.w);
    pk.z = pk2bf(hi.x, hi.y);
    pk.w = pk2bf(hi.z, hi.w);
    w2b[c] = pk;
}

template<bool WS>
struct __align__(16) Sm {
    // per-wave 8 KB region: dbf (selection phase) then h1 (MLP phase) — same-wave
    // program order makes the union safe with no barrier.
    union __align__(16) U {
        ushort dbf[NN];                 // top-16 distance bits per j
        ushort h1[KK * HID];            // MLP A-operand (32 edges x 128, swizzled)
    } uw[WPB];                          // 32 KB total
    uint32_t cand[WPB][CAP];            // 2 KB : per-wave (d16<<16)|j keys
    float    rads[WPB][KK];             // per-wave edge radial
    float    sedge[WPB][KK];            // per-wave edge scalar
    int      recvs[WPB][KK];            // per-wave neighbor ids
    uint32_t w2l[WS ? 4 : HID * 64];    // W2 LDS staging only in no-workspace path
};

template<bool WS>
__global__ __launch_bounds__(BLK) void egnn_main(
    const float* __restrict__ pos, const float* __restrict__ tptr,
    const float* __restrict__ W1,  const float* __restrict__ b1,
    const float* __restrict__ g1,  const float* __restrict__ W2,
    const float* __restrict__ b2,  const float* __restrict__ g2,
    const float* __restrict__ W3,  const float* __restrict__ b3,
    const uint4* __restrict__ w2b, float* __restrict__ out)
{
    __shared__ Sm<WS> sm;
    const int tid  = threadIdx.x;
    const int lane = tid & 63;
    const int wid  = tid >> 6;                  // 0..3: this wave / its node
    const int i    = blockIdx.x * WPB + wid;    // node handled by this wave
    const int l15  = lane & 15, lq = lane >> 4;

    const float ts  = tptr[0];
    const float b3s = b3[0];

    // closed-form RMS coefficients (wave-reduced -> lane-uniform):
    // sum_n (rad*a_n + c_n)^2 = rad^2*A2 + 2*rad*AC + C2
    float A2, AC, C2;
    {
        const float4 w1v = ((const float4*)W1)[lane];     // rows 2l,2l+1
        const float2 b1v = ((const float2*)b1)[lane];
        float t0 = ts * w1v.y + b1v.x;
        float t1 = ts * w1v.w + b1v.y;
        A2 = w1v.x*w1v.x + w1v.z*w1v.z;
        AC = w1v.x*t0    + w1v.z*t1;
        C2 = t0*t0       + t1*t1;
        #pragma unroll
        for (int m = 32; m >= 1; m >>= 1) {
            A2 += __shfl_xor(A2, m, 64);
            AC += __shfl_xor(AC, m, 64);
            C2 += __shfl_xor(C2, m, 64);
        }
    }

    if constexpr (!WS) {
        // fallback: stage W2 into LDS (bf16, 16B chunks XOR-swizzled by row&15)
        for (int idx = tid; idx < HID * 16; idx += BLK) {
            int row = idx >> 4, c = idx & 15;
            const float* src = W2 + row * HID + c * 8;
            float4 lo = *(const float4*)src;
            float4 hi = *(const float4*)(src + 4);
            uint4 pk;
            pk.x = pk2bf(lo.x, lo.y);
            pk.y = pk2bf(lo.z, lo.w);
            pk.z = pk2bf(hi.x, hi.y);
            pk.w = pk2bf(hi.z, hi.w);
            *((uint4*)&sm.w2l[row * 64 + 4 * (c ^ (row & 15))]) = pk;
        }
        __syncthreads();      // only barrier, fallback path only
    }

    const float px = pos[3*i], py = pos[3*i+1], pz = pos[3*i+2];
    const float4* p4 = (const float4*)pos;

    // self-exclusion coordinates (i is wave-uniform: one group, one lane, one c)
    const int  sgrp     = i >> 8;
    const bool selfLane = ((i >> 2) & 63) == lane;
    const int  selfc    = i & 3;

    // ---- pass 1: distances ONCE; d16 to per-wave LDS; per-lane sample min ----
    float mind = FINF;
    {
        ushort* dbf = sm.uw[wid].dbf;
        #pragma unroll 4
        for (int g = 0; g < 16; ++g) {
            float d[4];
            dist4(p4, g, lane, px, py, pz, d);
            if (g == sgrp && selfLane) {
                #pragma unroll
                for (int c = 0; c < 4; ++c)
                    if (c == selfc) d[c] = FINF;
            }
            uint32_t lo = (__float_as_uint(d[0]) >> 16) | (__float_as_uint(d[1]) & 0xffff0000u);
            uint32_t hi = (__float_as_uint(d[2]) >> 16) | (__float_as_uint(d[3]) & 0xffff0000u);
            *((uint2*)&dbf[g*256 + 4*lane]) = make_uint2(lo, hi);
            mind = fminf(fminf(fminf(mind, d[0]), fminf(d[1], d[2])), d[3]);
        }
    }
    const uint32_t m16 = __float_as_uint(mind) >> 16;

    // ---- v = 32nd smallest sample-min (16-bit radix search via ballot) ----
    // >=32 sample-mins at DISTINCT j (lanes own disjoint j sets, self excluded)
    // are <= v  =>  the 32 smallest (d16,j) keys all have d16 <= v.
    uint32_t v = 0;
    #pragma unroll
    for (int b = 15; b >= 0; --b) {
        uint32_t t = v | (1u << b);
        int nl = (int)__popcll(__ballot(m16 < t));
        if (nl < KK) v = t;
    }

    // ---- compaction: per-lane count -> one wave exclusive scan ->
    //      per-lane sequential slot writes. Slot ORDER is irrelevant
    //      (rank-select orders by key), only cnt and coverage matter. ----
    uint32_t cnt = 0;
    {
        const ushort* dbf = sm.uw[wid].dbf;
        uint32_t myc = 0;
        #pragma unroll 4
        for (int g = 0; g < 16; ++g) {
            uint2 w = *((const uint2*)&dbf[g*256 + 4*lane]);
            myc += (uint32_t)((w.x & 0xffffu) <= v);
            myc += (uint32_t)((w.x >> 16)     <= v);
            myc += (uint32_t)((w.y & 0xffffu) <= v);
            myc += (uint32_t)((w.y >> 16)     <= v);
        }
        // exclusive scan across the wave (6 shfl_up steps)
        uint32_t inc = myc;
        #pragma unroll
        for (int off = 1; off < 64; off <<= 1) {
            uint32_t y = __shfl_up(inc, off, 64);
            if (lane >= off) inc += y;
        }
        uint32_t slot = inc - myc;
        cnt = (uint32_t)__shfl((int)inc, 63, 64);
        // second pass: emit keys at per-lane consecutive slots
        if (myc) {
            #pragma unroll 4
            for (int g = 0; g < 16; ++g) {
                uint2 w = *((const uint2*)&dbf[g*256 + 4*lane]);
                uint32_t d16v[4] = {w.x & 0xffffu, w.x >> 16, w.y & 0xffffu, w.y >> 16};
                #pragma unroll
                for (int c = 0; c < 4; ++c) {
                    if (d16v[c] <= v) {
                        if (slot < CAP)
                            sm.cand[wid][slot] = (d16v[c] << 16)
                                               | (unsigned)(g*256 + 4*lane + c);
                        slot++;
                    }
                }
            }
        }
    }
    const int cntv = (int)cnt;

    if (cntv <= CAP) {
        // sentinel-fill cand[cntv..CAP): keys 0xFFFFFFFF exceed any real key
        // ((d16<<16)|j <= 0xffff0fff), so the rank loop can run fixed-trip
        // over all CAP entries with NO per-element bounds checks.
        for (int idx = cntv + lane; idx < CAP; idx += 64)
            sm.cand[wid][idx] = 0xffffffffu;

        // ---- rank-select: lane ranks cand[lane] and cand[64+lane] ----
        #pragma unroll
        for (int h = 0; h < 2; ++h) {
            int idx = h*64 + lane;
            if (idx < cntv) {
                uint32_t km = sm.cand[wid][idx];
                int rank = 0;
                #pragma unroll 4
                for (int q = 0; q < CAP; q += 16) {
                    const uint4* cp = (const uint4*)&sm.cand[wid][q];
                    uint4 u0 = cp[0];
                    uint4 u1 = cp[1];
                    uint4 u2 = cp[2];
                    uint4 u3 = cp[3];
                    rank += (u0.x < km) ? 1 : 0;
                    rank += (u0.y < km) ? 1 : 0;
                    rank += (u0.z < km) ? 1 : 0;
                    rank += (u0.w < km) ? 1 : 0;
                    rank += (u1.x < km) ? 1 : 0;
                    rank += (u1.y < km) ? 1 : 0;
                    rank += (u1.z < km) ? 1 : 0;
                    rank += (u1.w < km) ? 1 : 0;
                    rank += (u2.x < km) ? 1 : 0;
                    rank += (u2.y < km) ? 1 : 0;
                    rank += (u2.z < km) ? 1 : 0;
                    rank += (u2.w < km) ? 1 : 0;
                    rank += (u3.x < km) ? 1 : 0;
                    rank += (u3.y < km) ? 1 : 0;
                    rank += (u3.z < km) ? 1 : 0;
                    rank += (u3.w < km) ? 1 : 0;
                }
                if (rank < KK) sm.recvs[wid][rank] = (int)(km & 0xFFFFu);
            }
        }
    } else {
        // ---- cold fallback (overflow; ~never): exact wave-local argmin x32,
        //      per-lane 64-bit exclusion mask for its own j's (recompute) ----
        unsigned long long locmask = 0ull;
        if (selfLane)                          // dist4 no longer infs self
            locmask |= 1ull << ((sgrp << 2) | selfc);
        for (int it = 0; it < KK; ++it) {
            unsigned long long best = ~0ull;
            for (int g = 0; g < 16; ++g) {
                float d[4];
                dist4(p4, g, lane, px, py, pz, d);
                #pragma unroll
                for (int c = 0; c < 4; ++c) {
                    bool dead = ((locmask >> (g*4 + c)) & 1ull) != 0ull;
                    unsigned long long key = dead ? ~0ull
                        : ((((unsigned long long)__float_as_uint(d[c])) << 12)
                           | (unsigned)(g*256 + 4*lane + c));
                    best = best < key ? best : key;
                }
            }
            #pragma unroll
            for (int m = 32; m >= 1; m >>= 1) {
                unsigned long long o = __shfl_xor(best, m, 64);
                best = best < o ? best : o;
            }
            int j = (int)(best & 0xfffull);
            if (lane == 0) sm.recvs[wid][it] = j;
            if (((j >> 2) & 63) == lane)
                locmask |= 1ull << ((j >> 8) * 4 + (j & 3));
        }
    }

    // ---- edge gather: lane e < 32 holds neighbor e's geometry ----
    float cdx = 0.f, cdy = 0.f, cdz = 0.f;
    if (lane < KK) {
        int r = sm.recvs[wid][lane];
        cdx = px - pos[3*r];
        cdy = py - pos[3*r+1];
        cdz = pz - pos[3*r+2];
        float rad = __fadd_rn(__fadd_rn(__fmul_rn(cdx,cdx), __fmul_rn(cdy,cdy)),
                              __fmul_rn(cdz,cdz));
        sm.rads[wid][lane] = rad;
    }

    // ---- layer 1: all 32 edges of this node; lane = ch*4 + epr ----
    // h1 overwrites dbf (same union region) — all dbf reads completed above in
    // this wave's program order.
    {
        const int ch = lane >> 2, epr = lane & 3;
        float4 wA = ((const float4*)W1)[ch*4    ];
        float4 wB = ((const float4*)W1)[ch*4 + 1];
        float4 wC = ((const float4*)W1)[ch*4 + 2];
        float4 wD = ((const float4*)W1)[ch*4 + 3];
        float4 bA = ((const float4*)b1)[ch*2], bB = ((const float4*)b1)[ch*2 + 1];
        float4 gA = ((const float4*)g1)[ch*2], gB = ((const float4*)g1)[ch*2 + 1];
        float av[8] = {wA.x, wA.z, wB.x, wB.z, wC.x, wC.z, wD.x, wD.z};
        float cv[8] = {ts*wA.y + bA.x, ts*wA.w + bA.y, ts*wB.y + bA.z, ts*wB.w + bA.w,
                       ts*wC.y + bB.x, ts*wC.w + bB.y, ts*wD.y + bB.z, ts*wD.w + bB.w};
        float gv[8] = {gA.x, gA.y, gA.z, gA.w, gB.x, gB.y, gB.z, gB.w};
        uint4* h1q = (uint4*)&sm.uw[wid].h1[0];
        #pragma unroll
        for (int g = 0; g < 8; ++g) {
            int E = 4*g + epr;                    // 0..31
            float rad = sm.rads[wid][E];
            float sqv = rad*rad*A2 + 2.0f*rad*AC + C2;
            float rn  = fastrsq(sqv * (1.0f/HID) + 1e-5f);
            uint32_t pk[4];
            #pragma unroll
            for (int p = 0; p < 4; ++p) {
                float va = siluf((rad*av[2*p]   + cv[2*p])   * rn * gv[2*p]);
                float vb = siluf((rad*av[2*p+1] + cv[2*p+1]) * rn * gv[2*p+1]);
                pk[p] = pk2bf(va, vb);
            }
            h1q[E*16 + (ch ^ (E & 15))] = uint4{pk[0], pk[1], pk[2], pk[3]};
        }
    }
    // no barrier: h1[wid] written and read only by this wave (DS program order)

    // ---- epilogue constants: n = nt*16 + l15 (shared by both m-tile passes) ----
    float g2v[8], w3v[8], b2v[8];
    #pragma unroll
    for (int nt = 0; nt < 8; ++nt) {
        int n = nt*16 + l15;
        g2v[nt] = g2[n]; w3v[nt] = W3[n]; b2v[nt] = b2[n];
    }

    // ---- layer 2 + epilogue: two m-tile passes (16 edges each), all 8 n-tiles ----
    const bf16x8* h1v = (const bf16x8*)&sm.uw[wid].h1[0];
    #pragma unroll
    for (int mt = 0; mt < 2; ++mt) {
        f32x4 acc[8];
        #pragma unroll
        for (int nt = 0; nt < 8; ++nt) acc[nt] = f32x4{0.f, 0.f, 0.f, 0.f};
        const int m = mt*16 + l15;
        if constexpr (WS) {
            const bf16x8* bv = (const bf16x8*)w2b;
            #pragma unroll
            for (int kk = 0; kk < 4; ++kk) {
                bf16x8 af = h1v[m*16 + ((kk*4 + lq) ^ l15)];
                #pragma unroll
                for (int nt = 0; nt < 8; ++nt)
                    acc[nt] = __builtin_amdgcn_mfma_f32_16x16x32_bf16(
                                  af, bv[(nt*4 + kk)*64 + lane], acc[nt], 0, 0, 0);
            }
        } else {
            const bf16x8* w2v = (const bf16x8*)sm.w2l;    // [128][16 chunks]
            #pragma unroll
            for (int kk = 0; kk < 4; ++kk) {
                const int q = (kk*4 + lq) ^ l15;
                bf16x8 af = h1v[m*16 + q];
                #pragma unroll
                for (int nt = 0; nt < 8; ++nt)
                    acc[nt] = __builtin_amdgcn_mfma_f32_16x16x32_bf16(
                                  af, w2v[(nt*16 + l15)*16 + q], acc[nt], 0, 0, 0);
            }
        }

        // RMS over all 128 neurons: in-lane sum over 8 nt + shfl over l15 bits
        float ss[4];
        #pragma unroll
        for (int r = 0; r < 4; ++r) {
            float t = 0.f;
            #pragma unroll
            for (int nt = 0; nt < 8; ++nt) {
                float zz = acc[nt][r] + b2v[nt];
                acc[nt][r] = zz;
                t += zz*zz;
            }
            ss[r] = t;
        }
        #pragma unroll
        for (int m2 = 1; m2 <= 8; m2 <<= 1) {
            #pragma unroll
            for (int r = 0; r < 4; ++r) ss[r] += __shfl_xor(ss[r], m2, 64);
        }
        float sp[4];
        #pragma unroll
        for (int r = 0; r < 4; ++r) {
            float rn = fastrsq(ss[r] * (1.0f/HID) + 1e-5f);
            float t = 0.f;
            #pragma unroll
            for (int nt = 0; nt < 8; ++nt)
                t += siluf(acc[nt][r] * rn * g2v[nt]) * w3v[nt];
            sp[r] = t;
        }
        #pragma unroll
        for (int m2 = 1; m2 <= 8; m2 <<= 1) {
            #pragma unroll
            for (int r = 0; r < 4; ++r) sp[r] += __shfl_xor(sp[r], m2, 64);
        }
        if (l15 == 0) {
            #pragma unroll
            for (int r = 0; r < 4; ++r)
                sm.sedge[wid][mt*16 + lq*4 + r] = sp[r] + b3s;
        }
    }

    // ---- final: sum 32 edge messages (lane e holds cd of edge e) ----
    float mx = 0.f, my = 0.f, mz = 0.f;
    if (lane < KK) {
        float s = sm.sedge[wid][lane];
        mx = cdx * s; my = cdy * s; mz = cdz * s;
    }
    #pragma unroll
    for (int m = 32; m >= 1; m >>= 1) {
        mx += __shfl_xor(mx, m, 64);
        my += __shfl_xor(my, m, 64);
        mz += __shfl_xor(mz, m, 64);
    }
    if (lane == 0) {
        out[3*i    ] = px + mx * (1.0f/KK);
        out[3*i + 1] = py + my * (1.0f/KK);
        out[3*i + 2] = pz + mz * (1.0f/KK);
    }
}

extern "C" void kernel_launch(void* const* d_in, const int* in_sizes, int n_in,
                              void* d_out, int out_size, void* d_ws, size_t ws_size,
                              hipStream_t stream) {
    (void)in_sizes; (void)n_in; (void)out_size;
    const float* pos = (const float*)d_in[0];
    const float* t   = (const float*)d_in[1];
    const float* W1  = (const float*)d_in[2];
    const float* b1  = (const float*)d_in[3];
    const float* g1  = (const float*)d_in[4];
    const float* W2  = (const float*)d_in[5];
    const float* b2  = (const float*)d_in[6];
    const float* g2  = (const float*)d_in[7];
    const float* W3  = (const float*)d_in[8];
    const float* b3  = (const float*)d_in[9];
    float* out = (float*)d_out;

    if (d_ws != nullptr && ws_size >= 32768) {
        prepack_w2<<<8, 256, 0, stream>>>(W2, (uint4*)d_ws);
        egnn_main<true><<<GRID, BLK, 0, stream>>>(
            pos, t, W1, b1, g1, W2, b2, g2, W3, b3, (const uint4*)d_ws, out);
    } else {
        egnn_main<false><<<GRID, BLK, 0, stream>>>(
            pos, t, W1, b1, g1, W2, b2, g2, W3, b3, nullptr, out);
    }
}

// Round 4
// 107.978 us; speedup vs baseline: 1.0837x; 1.0123x over previous
//
#include <hip/hip_runtime.h>
#include <stdint.h>

#define NN   4096
#define KK   32
#define HID  128
#define BLK  256
#define WPB  4                 // waves per block = nodes per block
#define GRID (NN / WPB)
#define CAP  128

typedef unsigned short bf16_t;
typedef __attribute__((ext_vector_type(8))) short bf16x8;
typedef __attribute__((ext_vector_type(4))) float f32x4;
typedef __attribute__((ext_vector_type(2))) float f32x2;

#define FINF __uint_as_float(0x7f800000u)

// single-instruction packed f32->bf16 (RTNE), replaces manual bit-twiddle pairs
__device__ __forceinline__ uint32_t pk2bf(float lo, float hi) {
    uint32_t r;
    asm("v_cvt_pk_bf16_f32 %0, %1, %2" : "=v"(r) : "v"(lo), "v"(hi));
    return r;
}
// raw v_rcp_f32 / v_rsq_f32 (1-ulp approx): avoids the ~10-instr IEEE div /
// refined-rsqrt expansions. Values feed bf16-rounded or tolerance-dominated
// paths, so 1 ulp is harmless.
__device__ __forceinline__ float fastrcp(float x) {
    float r; asm("v_rcp_f32 %0, %1" : "=v"(r) : "v"(x)); return r;
}
__device__ __forceinline__ float fastrsq(float x) {
    float r; asm("v_rsq_f32 %0, %1" : "=v"(r) : "v"(x)); return r;
}
__device__ __forceinline__ float siluf(float x) {
    return x * fastrcp(1.0f + __expf(-x));
}

// 4 distances for j = g*256 + 4*lane + {0..3}, packed-fp32 (v_pk_mul/v_pk_add
// double-rate). contract(off) keeps the exact per-element IEEE chain
// mul,mul,mul,add,add == the reference __fmul_rn/__fadd_rn order.
__device__ __forceinline__ void dist4v(const float4* __restrict__ p4, int g, int lane,
                                       f32x2 pxv, f32x2 pyv, f32x2 pzv,
                                       f32x2& d01, f32x2& d23) {
    float4 f0 = p4[g*192 + 3*lane];
    float4 f1 = p4[g*192 + 3*lane + 1];
    float4 f2 = p4[g*192 + 3*lane + 2];
    f32x2 jx0 = {f0.x, f0.w}, jx1 = {f1.z, f2.y};
    f32x2 jy0 = {f0.y, f1.x}, jy1 = {f1.w, f2.z};
    f32x2 jz0 = {f0.z, f1.y}, jz1 = {f2.x, f2.w};
    {
#pragma clang fp contract(off)
        f32x2 dx0 = pxv - jx0, dy0 = pyv - jy0, dz0 = pzv - jz0;
        f32x2 dx1 = pxv - jx1, dy1 = pyv - jy1, dz1 = pzv - jz1;
        d01 = dx0*dx0 + dy0*dy0 + dz0*dz0;
        d23 = dx1*dx1 + dy1*dy1 + dz1*dz1;
    }
}
// scalar view (cold fallback only)
__device__ __forceinline__ void dist4s(const float4* __restrict__ p4, int g, int lane,
                                       float px, float py, float pz, float d[4]) {
    f32x2 pxv = {px, px}, pyv = {py, py}, pzv = {pz, pz};
    f32x2 a, b;
    dist4v(p4, g, lane, pxv, pyv, pzv, a, b);
    d[0] = a.x; d[1] = a.y; d[2] = b.x; d[3] = b.y;
}

// ---- prepack: W2 fp32 -> bf16 in MFMA B-fragment order (frag f = NT*4+kk) ----
__global__ __launch_bounds__(256) void prepack_w2(
    const float* __restrict__ W2, uint4* __restrict__ w2b)
{
    int c  = blockIdx.x * 256 + threadIdx.x;
    int f  = c >> 6, ln = c & 63;
    int NT = f >> 2, kk = f & 3;
    int row = NT*16 + (ln & 15);
    int k0  = kk*32 + (ln >> 4) * 8;
    const float* s = W2 + row * HID + k0;
    float4 lo = *(const float4*)s;
    float4 hi = *(const float4*)(s + 4);
    uint4 pk;
    pk.x = pk2bf(lo.x, lo.y);
    pk.y = pk2bf(lo.z, lo.w);
    pk.z = pk2bf(hi.x, hi.y);
    pk.w = pk2bf(hi.z, hi.w);
    w2b[c] = pk;
}

template<bool WS>
struct __align__(16) Sm {
    // per-wave 8 KB region: dbf (selection phase) then h1 (MLP phase) — same-wave
    // program order makes the union safe with no barrier.
    union __align__(16) U {
        ushort dbf[NN];                 // top-16 distance bits per j
        ushort h1[KK * HID];            // MLP A-operand (32 edges x 128, swizzled)
    } uw[WPB];                          // 32 KB total
    uint32_t cand[WPB][CAP];            // 2 KB : per-wave (d16<<16)|j keys
    float    rads[WPB][KK];             // per-wave edge radial
    float    sedge[WPB][KK];            // per-wave edge scalar
    int      recvs[WPB][KK];            // per-wave neighbor ids
    uint32_t w2l[WS ? 4 : HID * 64];    // W2 LDS staging only in no-workspace path
};

template<bool WS>
__global__ __launch_bounds__(BLK) void egnn_main(
    const float* __restrict__ pos, const float* __restrict__ tptr,
    const float* __restrict__ W1,  const float* __restrict__ b1,
    const float* __restrict__ g1,  const float* __restrict__ W2,
    const float* __restrict__ b2,  const float* __restrict__ g2,
    const float* __restrict__ W3,  const float* __restrict__ b3,
    const uint4* __restrict__ w2b, float* __restrict__ out)
{
    __shared__ Sm<WS> sm;
    const int tid  = threadIdx.x;
    const int lane = tid & 63;
    const int wid  = tid >> 6;                  // 0..3: this wave / its node
    const int i    = blockIdx.x * WPB + wid;    // node handled by this wave
    const int l15  = lane & 15, lq = lane >> 4;

    const float ts  = tptr[0];
    const float b3s = b3[0];

    // closed-form RMS coefficients (wave-reduced -> lane-uniform):
    // sum_n (rad*a_n + c_n)^2 = rad^2*A2 + 2*rad*AC + C2
    float A2, AC, C2;
    {
        const float4 w1v = ((const float4*)W1)[lane];     // rows 2l,2l+1
        const float2 b1v = ((const float2*)b1)[lane];
        float t0 = ts * w1v.y + b1v.x;
        float t1 = ts * w1v.w + b1v.y;
        A2 = w1v.x*w1v.x + w1v.z*w1v.z;
        AC = w1v.x*t0    + w1v.z*t1;
        C2 = t0*t0       + t1*t1;
        #pragma unroll
        for (int m = 32; m >= 1; m >>= 1) {
            A2 += __shfl_xor(A2, m, 64);
            AC += __shfl_xor(AC, m, 64);
            C2 += __shfl_xor(C2, m, 64);
        }
    }

    if constexpr (!WS) {
        // fallback: stage W2 into LDS (bf16, 16B chunks XOR-swizzled by row&15)
        for (int idx = tid; idx < HID * 16; idx += BLK) {
            int row = idx >> 4, c = idx & 15;
            const float* src = W2 + row * HID + c * 8;
            float4 lo = *(const float4*)src;
            float4 hi = *(const float4*)(src + 4);
            uint4 pk;
            pk.x = pk2bf(lo.x, lo.y);
            pk.y = pk2bf(lo.z, lo.w);
            pk.z = pk2bf(hi.x, hi.y);
            pk.w = pk2bf(hi.z, hi.w);
            *((uint4*)&sm.w2l[row * 64 + 4 * (c ^ (row & 15))]) = pk;
        }
        __syncthreads();      // only barrier, fallback path only
    }

    const float px = pos[3*i], py = pos[3*i+1], pz = pos[3*i+2];
    const float4* p4 = (const float4*)pos;
    const f32x2 pxv = {px, px}, pyv = {py, py}, pzv = {pz, pz};

    // self-exclusion coordinates (i is wave-uniform: one group, one lane, one c)
    const int  sgrp     = i >> 8;
    const bool selfLane = ((i >> 2) & 63) == lane;
    const int  selfc    = i & 3;

    // ---- pass 1: distances ONCE; d16 to per-wave LDS; per-lane sample min ----
    float mind = FINF;
    {
        ushort* dbf = sm.uw[wid].dbf;
        #pragma unroll 4
        for (int g = 0; g < 16; ++g) {
            f32x2 d01, d23;
            dist4v(p4, g, lane, pxv, pyv, pzv, d01, d23);
            if (g == sgrp && selfLane) {
                d01.x = (selfc == 0) ? FINF : d01.x;
                d01.y = (selfc == 1) ? FINF : d01.y;
                d23.x = (selfc == 2) ? FINF : d23.x;
                d23.y = (selfc == 3) ? FINF : d23.y;
            }
            uint2 u0 = *(uint2*)&d01;
            uint2 u1 = *(uint2*)&d23;
            uint32_t lo = (u0.x >> 16) | (u0.y & 0xffff0000u);
            uint32_t hi = (u1.x >> 16) | (u1.y & 0xffff0000u);
            *((uint2*)&dbf[g*256 + 4*lane]) = make_uint2(lo, hi);
            f32x2 mm = __builtin_elementwise_min(d01, d23);
            mind = fminf(mind, fminf(mm.x, mm.y));
        }
    }
    const uint32_t m16 = __float_as_uint(mind) >> 16;

    // ---- v = 32nd smallest sample-min (16-bit radix search via ballot) ----
    // >=32 sample-mins at DISTINCT j (lanes own disjoint j sets, self excluded)
    // are <= v  =>  the 32 smallest (d16,j) keys all have d16 <= v.
    uint32_t v = 0;
    #pragma unroll
    for (int b = 15; b >= 0; --b) {
        uint32_t t = v | (1u << b);
        int nl = (int)__popcll(__ballot(m16 < t));
        if (nl < KK) v = t;
    }

    // ---- compaction v3: SINGLE dbf pass computing count AND staging up to 6
    //      candidate keys per lane in named registers (no runtime indexing).
    //      Scan gives per-lane slot; keys written straight from registers.
    //      Rare overflow (any lane >6 staged) re-reads dbf (old path). ----
    uint32_t cnt = 0;
    uint32_t myc = 0;
    {
        const ushort* dbf = sm.uw[wid].dbf;
        uint32_t s0 = 0, s1 = 0, s2 = 0, s3 = 0, s4 = 0, s5 = 0;
        #pragma unroll 4
        for (int g = 0; g < 16; ++g) {
            uint2 w = *((const uint2*)&dbf[g*256 + 4*lane]);
            uint32_t e[4] = {w.x & 0xffffu, w.x >> 16, w.y & 0xffffu, w.y >> 16};
            #pragma unroll
            for (int c = 0; c < 4; ++c) {
                if (e[c] <= v) {
                    uint32_t key = (e[c] << 16) | (unsigned)(g*256 + 4*lane + c);
                    s0 = (myc == 0) ? key : s0;
                    s1 = (myc == 1) ? key : s1;
                    s2 = (myc == 2) ? key : s2;
                    s3 = (myc == 3) ? key : s3;
                    s4 = (myc == 4) ? key : s4;
                    s5 = (myc == 5) ? key : s5;
                    myc++;
                }
            }
        }
        // exclusive scan across the wave (6 shfl_up steps)
        uint32_t inc = myc;
        #pragma unroll
        for (int off = 1; off < 64; off <<= 1) {
            uint32_t y = (uint32_t)__shfl_up((int)inc, off, 64);
            if (lane >= off) inc += y;
        }
        uint32_t slot = inc - myc;
        cnt = (uint32_t)__shfl((int)inc, 63, 64);

        const bool ovf = __ballot(myc > 6) != 0ull;   // wave-uniform
        if (!ovf) {
            if (myc > 0 && slot     < CAP) sm.cand[wid][slot    ] = s0;
            if (myc > 1 && slot + 1 < CAP) sm.cand[wid][slot + 1] = s1;
            if (myc > 2 && slot + 2 < CAP) sm.cand[wid][slot + 2] = s2;
            if (myc > 3 && slot + 3 < CAP) sm.cand[wid][slot + 3] = s3;
            if (myc > 4 && slot + 4 < CAP) sm.cand[wid][slot + 4] = s4;
            if (myc > 5 && slot + 5 < CAP) sm.cand[wid][slot + 5] = s5;
        } else if (myc) {
            // rare: emit via re-read at per-lane consecutive slots
            #pragma unroll 4
            for (int g = 0; g < 16; ++g) {
                uint2 w = *((const uint2*)&dbf[g*256 + 4*lane]);
                uint32_t d16v[4] = {w.x & 0xffffu, w.x >> 16, w.y & 0xffffu, w.y >> 16};
                #pragma unroll
                for (int c = 0; c < 4; ++c) {
                    if (d16v[c] <= v) {
                        if (slot < CAP)
                            sm.cand[wid][slot] = (d16v[c] << 16)
                                               | (unsigned)(g*256 + 4*lane + c);
                        slot++;
                    }
                }
            }
        }
    }
    const int cntv = (int)cnt;

    if (cntv <= CAP) {
        // sentinel-fill cand[cntv..CAP): keys 0xFFFFFFFF exceed any real key
        // ((d16<<16)|j <= 0xffff0fff), so the rank loop runs block-wise with
        // NO per-element bounds checks; trip count is dynamic (typ. 3-5).
        for (int idx = cntv + lane; idx < CAP; idx += 64)
            sm.cand[wid][idx] = 0xffffffffu;

        const int nb = (cntv + 15) >> 4;      // 16-key blocks to scan
        // ---- rank-select: lane ranks cand[lane] and cand[64+lane] ----
        #pragma unroll
        for (int h = 0; h < 2; ++h) {
            int idx = h*64 + lane;
            if (idx < cntv) {
                uint32_t km = sm.cand[wid][idx];
                int rank = 0;
                for (int q = 0; q < nb; ++q) {
                    const uint4* cp = (const uint4*)&sm.cand[wid][q*16];
                    uint4 u0 = cp[0];
                    uint4 u1 = cp[1];
                    uint4 u2 = cp[2];
                    uint4 u3 = cp[3];
                    rank += (u0.x < km) ? 1 : 0;
                    rank += (u0.y < km) ? 1 : 0;
                    rank += (u0.z < km) ? 1 : 0;
                    rank += (u0.w < km) ? 1 : 0;
                    rank += (u1.x < km) ? 1 : 0;
                    rank += (u1.y < km) ? 1 : 0;
                    rank += (u1.z < km) ? 1 : 0;
                    rank += (u1.w < km) ? 1 : 0;
                    rank += (u2.x < km) ? 1 : 0;
                    rank += (u2.y < km) ? 1 : 0;
                    rank += (u2.z < km) ? 1 : 0;
                    rank += (u2.w < km) ? 1 : 0;
                    rank += (u3.x < km) ? 1 : 0;
                    rank += (u3.y < km) ? 1 : 0;
                    rank += (u3.z < km) ? 1 : 0;
                    rank += (u3.w < km) ? 1 : 0;
                }
                if (rank < KK) sm.recvs[wid][rank] = (int)(km & 0xFFFFu);
            }
        }
    } else {
        // ---- cold fallback (overflow; ~never): exact wave-local argmin x32,
        //      per-lane 64-bit exclusion mask for its own j's (recompute) ----
        unsigned long long locmask = 0ull;
        if (selfLane)                          // pass 1 infs self only in LDS
            locmask |= 1ull << ((sgrp << 2) | selfc);
        for (int it = 0; it < KK; ++it) {
            unsigned long long best = ~0ull;
            for (int g = 0; g < 16; ++g) {
                float d[4];
                dist4s(p4, g, lane, px, py, pz, d);
                #pragma unroll
                for (int c = 0; c < 4; ++c) {
                    bool dead = ((locmask >> (g*4 + c)) & 1ull) != 0ull;
                    unsigned long long key = dead ? ~0ull
                        : ((((unsigned long long)__float_as_uint(d[c])) << 12)
                           | (unsigned)(g*256 + 4*lane + c));
                    best = best < key ? best : key;
                }
            }
            #pragma unroll
            for (int m = 32; m >= 1; m >>= 1) {
                unsigned long long o = __shfl_xor(best, m, 64);
                best = best < o ? best : o;
            }
            int j = (int)(best & 0xfffull);
            if (lane == 0) sm.recvs[wid][it] = j;
            if (((j >> 2) & 63) == lane)
                locmask |= 1ull << ((j >> 8) * 4 + (j & 3));
        }
    }

    // ---- edge gather: lane e < 32 holds neighbor e's geometry ----
    float cdx = 0.f, cdy = 0.f, cdz = 0.f;
    if (lane < KK) {
        int r = sm.recvs[wid][lane];
        cdx = px - pos[3*r];
        cdy = py - pos[3*r+1];
        cdz = pz - pos[3*r+2];
        float rad = __fadd_rn(__fadd_rn(__fmul_rn(cdx,cdx), __fmul_rn(cdy,cdy)),
                              __fmul_rn(cdz,cdz));
        sm.rads[wid][lane] = rad;
    }

    // ---- layer 1: all 32 edges of this node; lane = ch*4 + epr ----
    // h1 overwrites dbf (same union region) — all dbf reads completed above in
    // this wave's program order.
    {
        const int ch = lane >> 2, epr = lane & 3;
        float4 wA = ((const float4*)W1)[ch*4    ];
        float4 wB = ((const float4*)W1)[ch*4 + 1];
        float4 wC = ((const float4*)W1)[ch*4 + 2];
        float4 wD = ((const float4*)W1)[ch*4 + 3];
        float4 bA = ((const float4*)b1)[ch*2], bB = ((const float4*)b1)[ch*2 + 1];
        float4 gA = ((const float4*)g1)[ch*2], gB = ((const float4*)g1)[ch*2 + 1];
        float av[8] = {wA.x, wA.z, wB.x, wB.z, wC.x, wC.z, wD.x, wD.z};
        float cv[8] = {ts*wA.y + bA.x, ts*wA.w + bA.y, ts*wB.y + bA.z, ts*wB.w + bA.w,
                       ts*wC.y + bB.x, ts*wC.w + bB.y, ts*wD.y + bB.z, ts*wD.w + bB.w};
        float gv[8] = {gA.x, gA.y, gA.z, gA.w, gB.x, gB.y, gB.z, gB.w};
        uint4* h1q = (uint4*)&sm.uw[wid].h1[0];
        #pragma unroll
        for (int g = 0; g < 8; ++g) {
            int E = 4*g + epr;                    // 0..31
            float rad = sm.rads[wid][E];
            float sqv = rad*rad*A2 + 2.0f*rad*AC + C2;
            float rn  = fastrsq(sqv * (1.0f/HID) + 1e-5f);
            uint32_t pk[4];
            #pragma unroll
            for (int p = 0; p < 4; ++p) {
                float va = siluf((rad*av[2*p]   + cv[2*p])   * rn * gv[2*p]);
                float vb = siluf((rad*av[2*p+1] + cv[2*p+1]) * rn * gv[2*p+1]);
                pk[p] = pk2bf(va, vb);
            }
            h1q[E*16 + (ch ^ (E & 15))] = uint4{pk[0], pk[1], pk[2], pk[3]};
        }
    }
    // no barrier: h1[wid] written and read only by this wave (DS program order)

    // ---- epilogue constants: n = nt*16 + l15 (shared by both m-tile passes) ----
    float g2v[8], w3v[8], b2v[8];
    #pragma unroll
    for (int nt = 0; nt < 8; ++nt) {
        int n = nt*16 + l15;
        g2v[nt] = g2[n]; w3v[nt] = W3[n]; b2v[nt] = b2[n];
    }

    // ---- layer 2 + epilogue: two m-tile passes (16 edges each), all 8 n-tiles ----
    const bf16x8* h1v = (const bf16x8*)&sm.uw[wid].h1[0];
    #pragma unroll
    for (int mt = 0; mt < 2; ++mt) {
        f32x4 acc[8];
        #pragma unroll
        for (int nt = 0; nt < 8; ++nt) acc[nt] = f32x4{0.f, 0.f, 0.f, 0.f};
        const int m = mt*16 + l15;
        if constexpr (WS) {
            const bf16x8* bv = (const bf16x8*)w2b;
            #pragma unroll
            for (int kk = 0; kk < 4; ++kk) {
                bf16x8 af = h1v[m*16 + ((kk*4 + lq) ^ l15)];
                #pragma unroll
                for (int nt = 0; nt < 8; ++nt)
                    acc[nt] = __builtin_amdgcn_mfma_f32_16x16x32_bf16(
                                  af, bv[(nt*4 + kk)*64 + lane], acc[nt], 0, 0, 0);
            }
        } else {
            const bf16x8* w2v = (const bf16x8*)sm.w2l;    // [128][16 chunks]
            #pragma unroll
            for (int kk = 0; kk < 4; ++kk) {
                const int q = (kk*4 + lq) ^ l15;
                bf16x8 af = h1v[m*16 + q];
                #pragma unroll
                for (int nt = 0; nt < 8; ++nt)
                    acc[nt] = __builtin_amdgcn_mfma_f32_16x16x32_bf16(
                                  af, w2v[(nt*16 + l15)*16 + q], acc[nt], 0, 0, 0);
            }
        }

        // RMS over all 128 neurons: in-lane sum over 8 nt + shfl over l15 bits
        float ss[4];
        #pragma unroll
        for (int r = 0; r < 4; ++r) {
            float t = 0.f;
            #pragma unroll
            for (int nt = 0; nt < 8; ++nt) {
                float zz = acc[nt][r] + b2v[nt];
                acc[nt][r] = zz;
                t += zz*zz;
            }
            ss[r] = t;
        }
        #pragma unroll
        for (int m2 = 1; m2 <= 8; m2 <<= 1) {
            #pragma unroll
            for (int r = 0; r < 4; ++r) ss[r] += __shfl_xor(ss[r], m2, 64);
        }
        float sp[4];
        #pragma unroll
        for (int r = 0; r < 4; ++r) {
            float rn = fastrsq(ss[r] * (1.0f/HID) + 1e-5f);
            float t = 0.f;
            #pragma unroll
            for (int nt = 0; nt < 8; ++nt)
                t += siluf(acc[nt][r] * rn * g2v[nt]) * w3v[nt];
            sp[r] = t;
        }
        #pragma unroll
        for (int m2 = 1; m2 <= 8; m2 <<= 1) {
            #pragma unroll
            for (int r = 0; r < 4; ++r) sp[r] += __shfl_xor(sp[r], m2, 64);
        }
        if (l15 == 0) {
            #pragma unroll
            for (int r = 0; r < 4; ++r)
                sm.sedge[wid][mt*16 + lq*4 + r] = sp[r] + b3s;
        }
    }

    // ---- final: sum 32 edge messages (lane e holds cd of edge e) ----
    float mx = 0.f, my = 0.f, mz = 0.f;
    if (lane < KK) {
        float s = sm.sedge[wid][lane];
        mx = cdx * s; my = cdy * s; mz = cdz * s;
    }
    #pragma unroll
    for (int m = 32; m >= 1; m >>= 1) {
        mx += __shfl_xor(mx, m, 64);
        my += __shfl_xor(my, m, 64);
        mz += __shfl_xor(mz, m, 64);
    }
    if (lane == 0) {
        out[3*i    ] = px + mx * (1.0f/KK);
        out[3*i + 1] = py + my * (1.0f/KK);
        out[3*i + 2] = pz + mz * (1.0f/KK);
    }
}

extern "C" void kernel_launch(void* const* d_in, const int* in_sizes, int n_in,
                              void* d_out, int out_size, void* d_ws, size_t ws_size,
                              hipStream_t stream) {
    (void)in_sizes; (void)n_in; (void)out_size;
    const float* pos = (const float*)d_in[0];
    const float* t   = (const float*)d_in[1];
    const float* W1  = (const float*)d_in[2];
    const float* b1  = (const float*)d_in[3];
    const float* g1  = (const float*)d_in[4];
    const float* W2  = (const float*)d_in[5];
    const float* b2  = (const float*)d_in[6];
    const float* g2  = (const float*)d_in[7];
    const float* W3  = (const float*)d_in[8];
    const float* b3  = (const float*)d_in[9];
    float* out = (float*)d_out;

    if (d_ws != nullptr && ws_size >= 32768) {
        prepack_w2<<<8, 256, 0, stream>>>(W2, (uint4*)d_ws);
        egnn_main<true><<<GRID, BLK, 0, stream>>>(
            pos, t, W1, b1, g1, W2, b2, g2, W3, b3, (const uint4*)d_ws, out);
    } else {
        egnn_main<false><<<GRID, BLK, 0, stream>>>(
            pos, t, W1, b1, g1, W2, b2, g2, W3, b3, nullptr, out);
    }
}

// Round 6
// 107.833 us; speedup vs baseline: 1.0852x; 1.0013x over previous
//
#include <hip/hip_runtime.h>
#include <stdint.h>

#define NN   4096
#define KK   32
#define HID  128
#define BLK  256
#define WPB  4                 // waves per block = nodes per block
#define GRID (NN / WPB)
#define CAP  128

typedef unsigned short bf16_t;
typedef __attribute__((ext_vector_type(8))) short bf16x8;
typedef __attribute__((ext_vector_type(4))) float f32x4;
typedef __attribute__((ext_vector_type(2))) float f32x2;

#define FINF __uint_as_float(0x7f800000u)

// single-instruction packed f32->bf16 (RTNE)
__device__ __forceinline__ uint32_t pk2bf(float lo, float hi) {
    uint32_t r;
    asm("v_cvt_pk_bf16_f32 %0, %1, %2" : "=v"(r) : "v"(lo), "v"(hi));
    return r;
}
// raw v_rcp_f32 / v_rsq_f32 (1-ulp approx)
__device__ __forceinline__ float fastrcp(float x) {
    float r; asm("v_rcp_f32 %0, %1" : "=v"(r) : "v"(x)); return r;
}
__device__ __forceinline__ float fastrsq(float x) {
    float r; asm("v_rsq_f32 %0, %1" : "=v"(r) : "v"(x)); return r;
}
__device__ __forceinline__ float siluf(float x) {
    return x * fastrcp(1.0f + __expf(-x));
}
// forced packed fp32 (double-rate); per-element IEEE semantics identical to
// scalar v_add_f32 / v_mul_f32.
__device__ __forceinline__ f32x2 pk_add(f32x2 a, f32x2 b) {
    f32x2 r; asm("v_pk_add_f32 %0, %1, %2" : "=v"(r) : "v"(a), "v"(b)); return r;
}
__device__ __forceinline__ f32x2 pk_sq(f32x2 a) {
    f32x2 r; asm("v_pk_mul_f32 %0, %1, %1" : "=v"(r) : "v"(a)); return r;
}

// exact scalar distance (cold fallback only) — reference IEEE chain
__device__ __forceinline__ void dist4s(const float4* __restrict__ p4, int g, int lane,
                                       float px, float py, float pz, float d[4]) {
    float4 f0 = p4[g*192 + 3*lane];
    float4 f1 = p4[g*192 + 3*lane + 1];
    float4 f2 = p4[g*192 + 3*lane + 2];
    float jx[4] = {f0.x, f0.w, f1.z, f2.y};
    float jy[4] = {f0.y, f1.x, f1.w, f2.z};
    float jz[4] = {f0.z, f1.y, f2.x, f2.w};
    #pragma unroll
    for (int c = 0; c < 4; ++c) {
        float dx = px - jx[c], dy = py - jy[c], dz = pz - jz[c];
        d[c] = __fadd_rn(__fadd_rn(__fmul_rn(dx,dx), __fmul_rn(dy,dy)),
                         __fmul_rn(dz,dz));
    }
}

// ---- prepack: W2 fp32 -> bf16 in MFMA B-fragment order (frag f = NT*4+kk) ----
__global__ __launch_bounds__(256) void prepack_w2(
    const float* __restrict__ W2, uint4* __restrict__ w2b)
{
    int c  = blockIdx.x * 256 + threadIdx.x;
    int f  = c >> 6, ln = c & 63;
    int NT = f >> 2, kk = f & 3;
    int row = NT*16 + (ln & 15);
    int k0  = kk*32 + (ln >> 4) * 8;
    const float* s = W2 + row * HID + k0;
    float4 lo = *(const float4*)s;
    float4 hi = *(const float4*)(s + 4);
    uint4 pk;
    pk.x = pk2bf(lo.x, lo.y);
    pk.y = pk2bf(lo.z, lo.w);
    pk.z = pk2bf(hi.x, hi.y);
    pk.w = pk2bf(hi.z, hi.w);
    w2b[c] = pk;
}

template<bool WS>
struct __align__(16) Sm {
    // per-wave 8 KB region: dbf (selection phase) then h1 (MLP phase) — same-wave
    // program order makes the union safe with no barrier.
    union __align__(16) U {
        ushort dbf[NN];                 // top-16 distance bits per j
        ushort h1[KK * HID];            // MLP A-operand (32 edges x 128, swizzled)
    } uw[WPB];                          // 32 KB total
    uint32_t cand[WPB][CAP];            // 2 KB : per-wave (d16<<16)|j keys
    uint32_t ccnt[WPB];                 // per-wave candidate counter (atomic slots)
    float    rads[WPB][KK];             // per-wave edge radial
    float    sedge[WPB][KK];            // per-wave edge scalar
    int      recvs[WPB][KK];            // per-wave neighbor ids
    uint32_t w2l[WS ? 4 : HID * 64];    // W2 LDS staging only in no-workspace path
};

template<bool WS>
__global__ __launch_bounds__(BLK) void egnn_main(
    const float* __restrict__ pos, const float* __restrict__ tptr,
    const float* __restrict__ W1,  const float* __restrict__ b1,
    const float* __restrict__ g1,  const float* __restrict__ W2,
    const float* __restrict__ b2,  const float* __restrict__ g2,
    const float* __restrict__ W3,  const float* __restrict__ b3,
    const uint4* __restrict__ w2b, float* __restrict__ out)
{
    __shared__ Sm<WS> sm;
    const int tid  = threadIdx.x;
    const int lane = tid & 63;
    const int wid  = tid >> 6;                  // 0..3: this wave / its node
    const int i    = blockIdx.x * WPB + wid;    // node handled by this wave
    const int l15  = lane & 15, lq = lane >> 4;

    if (lane == 0) sm.ccnt[wid] = 0;            // per-wave; DS program order

    const float ts  = tptr[0];
    const float b3s = b3[0];

    // closed-form RMS coefficients (wave-reduced -> lane-uniform):
    // sum_n (rad*a_n + c_n)^2 = rad^2*A2 + 2*rad*AC + C2
    float A2, AC, C2;
    {
        const float4 w1v = ((const float4*)W1)[lane];     // rows 2l,2l+1
        const float2 b1v = ((const float2*)b1)[lane];
        float t0 = ts * w1v.y + b1v.x;
        float t1 = ts * w1v.w + b1v.y;
        A2 = w1v.x*w1v.x + w1v.z*w1v.z;
        AC = w1v.x*t0    + w1v.z*t1;
        C2 = t0*t0       + t1*t1;
        #pragma unroll
        for (int m = 32; m >= 1; m >>= 1) {
            A2 += __shfl_xor(A2, m, 64);
            AC += __shfl_xor(AC, m, 64);
            C2 += __shfl_xor(C2, m, 64);
        }
    }

    if constexpr (!WS) {
        // fallback: stage W2 into LDS (bf16, 16B chunks XOR-swizzled by row&15)
        for (int idx = tid; idx < HID * 16; idx += BLK) {
            int row = idx >> 4, c = idx & 15;
            const float* src = W2 + row * HID + c * 8;
            float4 lo = *(const float4*)src;
            float4 hi = *(const float4*)(src + 4);
            uint4 pk;
            pk.x = pk2bf(lo.x, lo.y);
            pk.y = pk2bf(lo.z, lo.w);
            pk.z = pk2bf(hi.x, hi.y);
            pk.w = pk2bf(hi.z, hi.w);
            *((uint4*)&sm.w2l[row * 64 + 4 * (c ^ (row & 15))]) = pk;
        }
        __syncthreads();      // only barrier, fallback path only
    }

    const float px = pos[3*i], py = pos[3*i+1], pz = pos[3*i+2];
    const float4* p4 = (const float4*)pos;
    // negated position pairs: pk_add(J, nP) == J - P exactly; sign of the
    // difference is irrelevant post-square, value is bit-exact.
    const f32x2 nPxy = {-px, -py}, nPzx = {-pz, -px}, nPyz = {-py, -pz};

    // self-exclusion coordinates (i is wave-uniform: one group, one lane, one c)
    const int  sgrp     = i >> 8;
    const bool selfLane = ((i >> 2) & 63) == lane;
    const int  selfc    = i & 3;

    // ---- pass 1: distances ONCE (packed-f32, natural float4 pairs);
    //      d16 to per-wave LDS; per-lane sample min ----
    float mind = FINF;
    {
        ushort* dbf = sm.uw[wid].dbf;
        #pragma unroll 4
        for (int g = 0; g < 16; ++g) {
            float4 f0 = p4[g*192 + 3*lane];   // x0 y0 z0 x1
            float4 f1 = p4[g*192 + 3*lane+1]; // y1 z1 x2 y2
            float4 f2 = p4[g*192 + 3*lane+2]; // z2 x3 y3 z3
            f32x2 S0 = pk_sq(pk_add(f32x2{f0.x, f0.y}, nPxy));
            f32x2 S1 = pk_sq(pk_add(f32x2{f0.z, f0.w}, nPzx));
            f32x2 S2 = pk_sq(pk_add(f32x2{f1.x, f1.y}, nPyz));
            f32x2 S3 = pk_sq(pk_add(f32x2{f1.z, f1.w}, nPxy));
            f32x2 S4 = pk_sq(pk_add(f32x2{f2.x, f2.y}, nPzx));
            f32x2 S5 = pk_sq(pk_add(f32x2{f2.z, f2.w}, nPyz));
            // exact left-assoc chains (dx^2+dy^2)+dz^2 per j
            float d0 = S0.x + S0.y + S1.x;
            float d1 = S1.y + S2.x + S2.y;
            float d2 = S3.x + S3.y + S4.x;
            float d3 = S4.y + S5.x + S5.y;
            if (g == sgrp && selfLane) {
                d0 = (selfc == 0) ? FINF : d0;
                d1 = (selfc == 1) ? FINF : d1;
                d2 = (selfc == 2) ? FINF : d2;
                d3 = (selfc == 3) ? FINF : d3;
            }
            // pack top-16 bits pairs: one v_perm each
            uint32_t lo = __builtin_amdgcn_perm(__float_as_uint(d1),
                                                __float_as_uint(d0), 0x07060302u);
            uint32_t hi = __builtin_amdgcn_perm(__float_as_uint(d3),
                                                __float_as_uint(d2), 0x07060302u);
            *((uint2*)&dbf[g*256 + 4*lane]) = make_uint2(lo, hi);
            mind = fminf(fminf(fminf(mind, d0), fminf(d1, d2)), d3);
        }
    }
    const uint32_t m16 = __float_as_uint(mind) >> 16;

    // ---- v = 32nd smallest sample-min (16-bit radix search via ballot) ----
    // >=32 sample-mins at DISTINCT j (lanes own disjoint j sets, self excluded)
    // are <= v  =>  the 32 smallest (d16,j) keys all have d16 <= v.
    uint32_t v = 0;
    #pragma unroll
    for (int b = 15; b >= 0; --b) {
        uint32_t t = v | (1u << b);
        int nl = (int)__popcll(__ballot(m16 < t));
        if (nl < KK) v = t;
    }

    // ---- compaction v4: ONE pass, slots via per-wave LDS atomic. Slot ORDER
    //      is irrelevant (rank-select orders by key), so no scan/staging.
    //      Key trick: k=(d16<<16)|j compared vs vk=(v<<16)|0xffff avoids
    //      unpacking d16 (k<=vk  <=>  d16<=v, since j<=0xfff). ----
    uint32_t cnt;
    {
        const ushort* dbf = sm.uw[wid].dbf;
        const uint32_t vk  = (v << 16) | 0xffffu;
        const uint32_t jb0 = 4*lane;
        #pragma unroll 4
        for (int g = 0; g < 16; ++g) {
            uint2 w = *((const uint2*)&dbf[g*256 + 4*lane]);
            uint32_t jb = jb0 + g*256;
            uint32_t k0 = (w.x << 16) | jb;
            uint32_t k1 = (w.x & 0xffff0000u) | (jb + 1);
            uint32_t k2 = (w.y << 16) | (jb + 2);
            uint32_t k3 = (w.y & 0xffff0000u) | (jb + 3);
            if (k0 <= vk) { uint32_t s = atomicAdd(&sm.ccnt[wid], 1u);
                            if (s < CAP) sm.cand[wid][s] = k0; }
            if (k1 <= vk) { uint32_t s = atomicAdd(&sm.ccnt[wid], 1u);
                            if (s < CAP) sm.cand[wid][s] = k1; }
            if (k2 <= vk) { uint32_t s = atomicAdd(&sm.ccnt[wid], 1u);
                            if (s < CAP) sm.cand[wid][s] = k2; }
            if (k3 <= vk) { uint32_t s = atomicAdd(&sm.ccnt[wid], 1u);
                            if (s < CAP) sm.cand[wid][s] = k3; }
        }
        cnt = sm.ccnt[wid];   // this wave's atomics precede in DS program order
    }
    const int cntv = (int)cnt;

    if (cntv <= CAP) {
        // sentinel-fill cand[cntv..CAP): keys 0xFFFFFFFF exceed any real key
        // ((d16<<16)|j <= 0xffff0fff), so the rank loop runs block-wise with
        // NO per-element bounds checks; trip count is dynamic (typ. 3-5).
        for (int idx = cntv + lane; idx < CAP; idx += 64)
            sm.cand[wid][idx] = 0xffffffffu;

        const int nb = (cntv + 15) >> 4;      // 16-key blocks to scan
        // ---- rank-select: lane ranks cand[lane] and cand[64+lane] ----
        #pragma unroll
        for (int h = 0; h < 2; ++h) {
            int idx = h*64 + lane;
            if (idx < cntv) {
                uint32_t km = sm.cand[wid][idx];
                int rank = 0;
                for (int q = 0; q < nb; ++q) {
                    const uint4* cp = (const uint4*)&sm.cand[wid][q*16];
                    uint4 u0 = cp[0];
                    uint4 u1 = cp[1];
                    uint4 u2 = cp[2];
                    uint4 u3 = cp[3];
                    rank += (u0.x < km) ? 1 : 0;
                    rank += (u0.y < km) ? 1 : 0;
                    rank += (u0.z < km) ? 1 : 0;
                    rank += (u0.w < km) ? 1 : 0;
                    rank += (u1.x < km) ? 1 : 0;
                    rank += (u1.y < km) ? 1 : 0;
                    rank += (u1.z < km) ? 1 : 0;
                    rank += (u1.w < km) ? 1 : 0;
                    rank += (u2.x < km) ? 1 : 0;
                    rank += (u2.y < km) ? 1 : 0;
                    rank += (u2.z < km) ? 1 : 0;
                    rank += (u2.w < km) ? 1 : 0;
                    rank += (u3.x < km) ? 1 : 0;
                    rank += (u3.y < km) ? 1 : 0;
                    rank += (u3.z < km) ? 1 : 0;
                    rank += (u3.w < km) ? 1 : 0;
                }
                if (rank < KK) sm.recvs[wid][rank] = (int)(km & 0xFFFFu);
            }
        }
    } else {
        // ---- cold fallback (overflow; ~never): exact wave-local argmin x32,
        //      per-lane 64-bit exclusion mask for its own j's (recompute) ----
        unsigned long long locmask = 0ull;
        if (selfLane)                          // exclude self
            locmask |= 1ull << ((sgrp << 2) | selfc);
        for (int it = 0; it < KK; ++it) {
            unsigned long long best = ~0ull;
            for (int g = 0; g < 16; ++g) {
                float d[4];
                dist4s(p4, g, lane, px, py, pz, d);
                #pragma unroll
                for (int c = 0; c < 4; ++c) {
                    bool dead = ((locmask >> (g*4 + c)) & 1ull) != 0ull;
                    unsigned long long key = dead ? ~0ull
                        : ((((unsigned long long)__float_as_uint(d[c])) << 12)
                           | (unsigned)(g*256 + 4*lane + c));
                    best = best < key ? best : key;
                }
            }
            #pragma unroll
            for (int m = 32; m >= 1; m >>= 1) {
                unsigned long long o = __shfl_xor(best, m, 64);
                best = best < o ? best : o;
            }
            int j = (int)(best & 0xfffull);
            if (lane == 0) sm.recvs[wid][it] = j;
            if (((j >> 2) & 63) == lane)
                locmask |= 1ull << ((j >> 8) * 4 + (j & 3));
        }
    }

    // ---- edge gather: lane e < 32 holds neighbor e's geometry ----
    float cdx = 0.f, cdy = 0.f, cdz = 0.f;
    if (lane < KK) {
        int r = sm.recvs[wid][lane];
        cdx = px - pos[3*r];
        cdy = py - pos[3*r+1];
        cdz = pz - pos[3*r+2];
        float rad = __fadd_rn(__fadd_rn(__fmul_rn(cdx,cdx), __fmul_rn(cdy,cdy)),
                              __fmul_rn(cdz,cdz));
        sm.rads[wid][lane] = rad;
    }

    // ---- layer 1: all 32 edges of this node; lane = ch*4 + epr ----
    // h1 overwrites dbf (same union region) — all dbf reads completed above in
    // this wave's program order.
    {
        const int ch = lane >> 2, epr = lane & 3;
        float4 wA = ((const float4*)W1)[ch*4    ];
        float4 wB = ((const float4*)W1)[ch*4 + 1];
        float4 wC = ((const float4*)W1)[ch*4 + 2];
        float4 wD = ((const float4*)W1)[ch*4 + 3];
        float4 bA = ((const float4*)b1)[ch*2], bB = ((const float4*)b1)[ch*2 + 1];
        float4 gA = ((const float4*)g1)[ch*2], gB = ((const float4*)g1)[ch*2 + 1];
        float av[8] = {wA.x, wA.z, wB.x, wB.z, wC.x, wC.z, wD.x, wD.z};
        float cv[8] = {ts*wA.y + bA.x, ts*wA.w + bA.y, ts*wB.y + bA.z, ts*wB.w + bA.w,
                       ts*wC.y + bB.x, ts*wC.w + bB.y, ts*wD.y + bB.z, ts*wD.w + bB.w};
        float gv[8] = {gA.x, gA.y, gA.z, gA.w, gB.x, gB.y, gB.z, gB.w};
        uint4* h1q = (uint4*)&sm.uw[wid].h1[0];
        #pragma unroll
        for (int g = 0; g < 8; ++g) {
            int E = 4*g + epr;                    // 0..31
            float rad = sm.rads[wid][E];
            float sqv = rad*rad*A2 + 2.0f*rad*AC + C2;
            float rn  = fastrsq(sqv * (1.0f/HID) + 1e-5f);
            uint32_t pk[4];
            #pragma unroll
            for (int p = 0; p < 4; ++p) {
                float va = siluf((rad*av[2*p]   + cv[2*p])   * rn * gv[2*p]);
                float vb = siluf((rad*av[2*p+1] + cv[2*p+1]) * rn * gv[2*p+1]);
                pk[p] = pk2bf(va, vb);
            }
            h1q[E*16 + (ch ^ (E & 15))] = uint4{pk[0], pk[1], pk[2], pk[3]};
        }
    }
    // no barrier: h1[wid] written and read only by this wave (DS program order)

    // ---- epilogue constants: n = nt*16 + l15 (shared by both m-tile passes) ----
    float g2v[8], w3v[8], b2v[8];
    #pragma unroll
    for (int nt = 0; nt < 8; ++nt) {
        int n = nt*16 + l15;
        g2v[nt] = g2[n]; w3v[nt] = W3[n]; b2v[nt] = b2[n];
    }

    // ---- layer 2 + epilogue: two m-tile passes (16 edges each), all 8 n-tiles ----
    const bf16x8* h1v = (const bf16x8*)&sm.uw[wid].h1[0];
    #pragma unroll
    for (int mt = 0; mt < 2; ++mt) {
        f32x4 acc[8];
        #pragma unroll
        for (int nt = 0; nt < 8; ++nt) acc[nt] = f32x4{0.f, 0.f, 0.f, 0.f};
        const int m = mt*16 + l15;
        if constexpr (WS) {
            const bf16x8* bv = (const bf16x8*)w2b;
            #pragma unroll
            for (int kk = 0; kk < 4; ++kk) {
                bf16x8 af = h1v[m*16 + ((kk*4 + lq) ^ l15)];
                #pragma unroll
                for (int nt = 0; nt < 8; ++nt)
                    acc[nt] = __builtin_amdgcn_mfma_f32_16x16x32_bf16(
                                  af, bv[(nt*4 + kk)*64 + lane], acc[nt], 0, 0, 0);
            }
        } else {
            const bf16x8* w2v = (const bf16x8*)sm.w2l;    // [128][16 chunks]
            #pragma unroll
            for (int kk = 0; kk < 4; ++kk) {
                const int q = (kk*4 + lq) ^ l15;
                bf16x8 af = h1v[m*16 + q];
                #pragma unroll
                for (int nt = 0; nt < 8; ++nt)
                    acc[nt] = __builtin_amdgcn_mfma_f32_16x16x32_bf16(
                                  af, w2v[(nt*16 + l15)*16 + q], acc[nt], 0, 0, 0);
            }
        }

        // RMS over all 128 neurons: in-lane sum over 8 nt + shfl over l15 bits
        float ss[4];
        #pragma unroll
        for (int r = 0; r < 4; ++r) {
            float t = 0.f;
            #pragma unroll
            for (int nt = 0; nt < 8; ++nt) {
                float zz = acc[nt][r] + b2v[nt];
                acc[nt][r] = zz;
                t += zz*zz;
            }
            ss[r] = t;
        }
        #pragma unroll
        for (int m2 = 1; m2 <= 8; m2 <<= 1) {
            #pragma unroll
            for (int r = 0; r < 4; ++r) ss[r] += __shfl_xor(ss[r], m2, 64);
        }
        float sp[4];
        #pragma unroll
        for (int r = 0; r < 4; ++r) {
            float rn = fastrsq(ss[r] * (1.0f/HID) + 1e-5f);
            float t = 0.f;
            #pragma unroll
            for (int nt = 0; nt < 8; ++nt)
                t += siluf(acc[nt][r] * rn * g2v[nt]) * w3v[nt];
            sp[r] = t;
        }
        #pragma unroll
        for (int m2 = 1; m2 <= 8; m2 <<= 1) {
            #pragma unroll
            for (int r = 0; r < 4; ++r) sp[r] += __shfl_xor(sp[r], m2, 64);
        }
        if (l15 == 0) {
            #pragma unroll
            for (int r = 0; r < 4; ++r)
                sm.sedge[wid][mt*16 + lq*4 + r] = sp[r] + b3s;
        }
    }

    // ---- final: sum 32 edge messages (lane e holds cd of edge e) ----
    float mx = 0.f, my = 0.f, mz = 0.f;
    if (lane < KK) {
        float s = sm.sedge[wid][lane];
        mx = cdx * s; my = cdy * s; mz = cdz * s;
    }
    #pragma unroll
    for (int m = 32; m >= 1; m >>= 1) {
        mx += __shfl_xor(mx, m, 64);
        my += __shfl_xor(my, m, 64);
        mz += __shfl_xor(mz, m, 64);
    }
    if (lane == 0) {
        out[3*i    ] = px + mx * (1.0f/KK);
        out[3*i + 1] = py + my * (1.0f/KK);
        out[3*i + 2] = pz + mz * (1.0f/KK);
    }
}

extern "C" void kernel_launch(void* const* d_in, const int* in_sizes, int n_in,
                              void* d_out, int out_size, void* d_ws, size_t ws_size,
                              hipStream_t stream) {
    (void)in_sizes; (void)n_in; (void)out_size;
    const float* pos = (const float*)d_in[0];
    const float* t   = (const float*)d_in[1];
    const float* W1  = (const float*)d_in[2];
    const float* b1  = (const float*)d_in[3];
    const float* g1  = (const float*)d_in[4];
    const float* W2  = (const float*)d_in[5];
    const float* b2  = (const float*)d_in[6];
    const float* g2  = (const float*)d_in[7];
    const float* W3  = (const float*)d_in[8];
    const float* b3  = (const float*)d_in[9];
    float* out = (float*)d_out;

    if (d_ws != nullptr && ws_size >= 32768) {
        prepack_w2<<<8, 256, 0, stream>>>(W2, (uint4*)d_ws);
        egnn_main<true><<<GRID, BLK, 0, stream>>>(
            pos, t, W1, b1, g1, W2, b2, g2, W3, b3, (const uint4*)d_ws, out);
    } else {
        egnn_main<false><<<GRID, BLK, 0, stream>>>(
            pos, t, W1, b1, g1, W2, b2, g2, W3, b3, nullptr, out);
    }
}

// Round 8
// 105.613 us; speedup vs baseline: 1.1080x; 1.0210x over previous
//
#include <hip/hip_runtime.h>
#include <stdint.h>

#define NN   4096
#define KK   32
#define HID  128
#define BLK  256
#define WPB  4                 // waves per block = nodes per block
#define GRID (NN / WPB)
#define CAP  128

typedef unsigned short bf16_t;
typedef __attribute__((ext_vector_type(8))) short bf16x8;
typedef __attribute__((ext_vector_type(4))) float f32x4;
typedef __attribute__((ext_vector_type(2))) float f32x2;

#define FINF __uint_as_float(0x7f800000u)

// single-instruction packed f32->bf16 (RTNE)
__device__ __forceinline__ uint32_t pk2bf(float lo, float hi) {
    uint32_t r;
    asm("v_cvt_pk_bf16_f32 %0, %1, %2" : "=v"(r) : "v"(lo), "v"(hi));
    return r;
}
// raw v_rcp_f32 / v_rsq_f32 (1-ulp approx)
__device__ __forceinline__ float fastrcp(float x) {
    float r; asm("v_rcp_f32 %0, %1" : "=v"(r) : "v"(x)); return r;
}
__device__ __forceinline__ float fastrsq(float x) {
    float r; asm("v_rsq_f32 %0, %1" : "=v"(r) : "v"(x)); return r;
}
__device__ __forceinline__ float siluf(float x) {
    return x * fastrcp(1.0f + __expf(-x));
}
// forced packed fp32 (double-rate); per-element IEEE semantics identical to
// scalar v_add_f32 / v_mul_f32.
__device__ __forceinline__ f32x2 pk_add(f32x2 a, f32x2 b) {
    f32x2 r; asm("v_pk_add_f32 %0, %1, %2" : "=v"(r) : "v"(a), "v"(b)); return r;
}
__device__ __forceinline__ f32x2 pk_sq(f32x2 a) {
    f32x2 r; asm("v_pk_mul_f32 %0, %1, %1" : "=v"(r) : "v"(a)); return r;
}

// ---- DPP reductions: VALU-latency cross-lane sums (off the LDS pipe). ----
// rowsum16: every lane of each 16-lane row ends with the row sum
// (ror-chain tree; fp grouping differs per lane by rotation — harmless here,
// consumers are per-lane rsqrt/bf16-rounded paths or single-lane writes).
template<int CTRL>
__device__ __forceinline__ float rsum_step(float x) {
    return x + __int_as_float(__builtin_amdgcn_update_dpp(
        0, __float_as_int(x), CTRL, 0xF, 0xF, true));
}
__device__ __forceinline__ float rowsum16(float x) {
    x = rsum_step<0xB1>(x);    // quad_perm [1,0,3,2]  (xor 1)
    x = rsum_step<0x4E>(x);    // quad_perm [2,3,0,1]  (xor 2)
    x = rsum_step<0x124>(x);   // row_ror:4
    x = rsum_step<0x128>(x);   // row_ror:8
    return x;
}
__device__ __forceinline__ float wsum64(float x) {
    x = rowsum16(x);
    x += __shfl_xor(x, 16, 64);
    x += __shfl_xor(x, 32, 64);
    return x;
}

// exact scalar distance (cold fallback only) — reference IEEE chain
__device__ __forceinline__ void dist4s(const float4* __restrict__ p4, int g, int lane,
                                       float px, float py, float pz, float d[4]) {
    float4 f0 = p4[g*192 + 3*lane];
    float4 f1 = p4[g*192 + 3*lane + 1];
    float4 f2 = p4[g*192 + 3*lane + 2];
    float jx[4] = {f0.x, f0.w, f1.z, f2.y};
    float jy[4] = {f0.y, f1.x, f1.w, f2.z};
    float jz[4] = {f0.z, f1.y, f2.x, f2.w};
    #pragma unroll
    for (int c = 0; c < 4; ++c) {
        float dx = px - jx[c], dy = py - jy[c], dz = pz - jz[c];
        d[c] = __fadd_rn(__fadd_rn(__fmul_rn(dx,dx), __fmul_rn(dy,dy)),
                         __fmul_rn(dz,dz));
    }
}

// ---- prepack: W2 fp32 -> bf16 in MFMA B-fragment order (frag f = NT*4+kk) ----
__global__ __launch_bounds__(256) void prepack_w2(
    const float* __restrict__ W2, uint4* __restrict__ w2b)
{
    int c  = blockIdx.x * 256 + threadIdx.x;
    int f  = c >> 6, ln = c & 63;
    int NT = f >> 2, kk = f & 3;
    int row = NT*16 + (ln & 15);
    int k0  = kk*32 + (ln >> 4) * 8;
    const float* s = W2 + row * HID + k0;
    float4 lo = *(const float4*)s;
    float4 hi = *(const float4*)(s + 4);
    uint4 pk;
    pk.x = pk2bf(lo.x, lo.y);
    pk.y = pk2bf(lo.z, lo.w);
    pk.z = pk2bf(hi.x, hi.y);
    pk.w = pk2bf(hi.z, hi.w);
    w2b[c] = pk;
}

template<bool WS>
struct __align__(16) Sm {
    // per-wave 8 KB region: dbf (selection phase) then h1 (MLP phase) — same-wave
    // program order makes the union safe with no barrier.
    union __align__(16) U {
        ushort dbf[NN];                 // top-16 distance bits per j
        ushort h1[KK * HID];            // MLP A-operand (32 edges x 128, swizzled)
    } uw[WPB];                          // 32 KB total
    uint32_t cand[WPB][CAP];            // 2 KB : per-wave (d16<<16)|j keys
    uint32_t ccnt[WPB];                 // per-wave candidate counter (atomic slots)
    float    rads[WPB][KK];             // per-wave edge radial
    float    sedge[WPB][KK];            // per-wave edge scalar
    int      recvs[WPB][KK];            // per-wave neighbor ids
    uint32_t w2l[WS ? 4 : HID * 64];    // W2 LDS staging only in no-workspace path
};

template<bool WS>
__global__ __launch_bounds__(BLK) void egnn_main(
    const float* __restrict__ pos, const float* __restrict__ tptr,
    const float* __restrict__ W1,  const float* __restrict__ b1,
    const float* __restrict__ g1,  const float* __restrict__ W2,
    const float* __restrict__ b2,  const float* __restrict__ g2,
    const float* __restrict__ W3,  const float* __restrict__ b3,
    const uint4* __restrict__ w2b, float* __restrict__ out)
{
    __shared__ Sm<WS> sm;
    const int tid  = threadIdx.x;
    const int lane = tid & 63;
    const int wid  = tid >> 6;                  // 0..3: this wave / its node
    const int i    = blockIdx.x * WPB + wid;    // node handled by this wave
    const int l15  = lane & 15, lq = lane >> 4;

    // ---- phase stagger: co-resident blocks on a CU start ~700cy apart so
    //      their (identical) stall points interleave instead of colliding.
    //      Covers both depth-packed (b&3) and breadth-first (b>>8) block->CU
    //      mappings; uniform per block, so barriers stay safe.
    //      (s_sleep needs a constant imm -> loop a constant sleep ph times.)
    {
        const int ph = ((blockIdx.x & 3) + (blockIdx.x >> 8)) & 3;
        for (int k = 0; k < ph; ++k) __builtin_amdgcn_s_sleep(11);  // ~704cy each
    }

    if (lane == 0) sm.ccnt[wid] = 0;            // per-wave; DS program order

    const float ts  = tptr[0];
    const float b3s = b3[0];

    // closed-form RMS coefficients (wave-reduced -> lane-uniform):
    // sum_n (rad*a_n + c_n)^2 = rad^2*A2 + 2*rad*AC + C2
    float A2, AC, C2;
    {
        const float4 w1v = ((const float4*)W1)[lane];     // rows 2l,2l+1
        const float2 b1v = ((const float2*)b1)[lane];
        float t0 = ts * w1v.y + b1v.x;
        float t1 = ts * w1v.w + b1v.y;
        A2 = wsum64(w1v.x*w1v.x + w1v.z*w1v.z);
        AC = wsum64(w1v.x*t0    + w1v.z*t1);
        C2 = wsum64(t0*t0       + t1*t1);
    }

    if constexpr (!WS) {
        // fallback: stage W2 into LDS (bf16, 16B chunks XOR-swizzled by row&15)
        for (int idx = tid; idx < HID * 16; idx += BLK) {
            int row = idx >> 4, c = idx & 15;
            const float* src = W2 + row * HID + c * 8;
            float4 lo = *(const float4*)src;
            float4 hi = *(const float4*)(src + 4);
            uint4 pk;
            pk.x = pk2bf(lo.x, lo.y);
            pk.y = pk2bf(lo.z, lo.w);
            pk.z = pk2bf(hi.x, hi.y);
            pk.w = pk2bf(hi.z, hi.w);
            *((uint4*)&sm.w2l[row * 64 + 4 * (c ^ (row & 15))]) = pk;
        }
        __syncthreads();      // only barrier, fallback path only
    }

    const float px = pos[3*i], py = pos[3*i+1], pz = pos[3*i+2];
    const float4* p4 = (const float4*)pos;
    // negated position pairs: pk_add(J, nP) == J - P exactly; sign of the
    // difference is irrelevant post-square, value is bit-exact.
    const f32x2 nPxy = {-px, -py}, nPzx = {-pz, -px}, nPyz = {-py, -pz};

    // self-exclusion coordinates (i is wave-uniform: one group, one lane, one c)
    const int  sgrp     = i >> 8;
    const bool selfLane = ((i >> 2) & 63) == lane;
    const int  selfc    = i & 3;

    // ---- pass 1: distances ONCE (packed-f32, natural float4 pairs);
    //      d16 to per-wave LDS; per-lane sample min ----
    float mind = FINF;
    {
        ushort* dbf = sm.uw[wid].dbf;
        #pragma unroll 4
        for (int g = 0; g < 16; ++g) {
            float4 f0 = p4[g*192 + 3*lane];   // x0 y0 z0 x1
            float4 f1 = p4[g*192 + 3*lane+1]; // y1 z1 x2 y2
            float4 f2 = p4[g*192 + 3*lane+2]; // z2 x3 y3 z3
            f32x2 S0 = pk_sq(pk_add(f32x2{f0.x, f0.y}, nPxy));
            f32x2 S1 = pk_sq(pk_add(f32x2{f0.z, f0.w}, nPzx));
            f32x2 S2 = pk_sq(pk_add(f32x2{f1.x, f1.y}, nPyz));
            f32x2 S3 = pk_sq(pk_add(f32x2{f1.z, f1.w}, nPxy));
            f32x2 S4 = pk_sq(pk_add(f32x2{f2.x, f2.y}, nPzx));
            f32x2 S5 = pk_sq(pk_add(f32x2{f2.z, f2.w}, nPyz));
            // exact left-assoc chains (dx^2+dy^2)+dz^2 per j
            float d0 = S0.x + S0.y + S1.x;
            float d1 = S1.y + S2.x + S2.y;
            float d2 = S3.x + S3.y + S4.x;
            float d3 = S4.y + S5.x + S5.y;
            if (g == sgrp && selfLane) {
                d0 = (selfc == 0) ? FINF : d0;
                d1 = (selfc == 1) ? FINF : d1;
                d2 = (selfc == 2) ? FINF : d2;
                d3 = (selfc == 3) ? FINF : d3;
            }
            // pack top-16 bits pairs: one v_perm each
            uint32_t lo = __builtin_amdgcn_perm(__float_as_uint(d1),
                                                __float_as_uint(d0), 0x07060302u);
            uint32_t hi = __builtin_amdgcn_perm(__float_as_uint(d3),
                                                __float_as_uint(d2), 0x07060302u);
            *((uint2*)&dbf[g*256 + 4*lane]) = make_uint2(lo, hi);
            mind = fminf(fminf(fminf(mind, d0), fminf(d1, d2)), d3);
        }
    }
    const uint32_t m16 = __float_as_uint(mind) >> 16;

    // ---- v = 32nd smallest sample-min (16-bit radix search via ballot) ----
    // >=32 sample-mins at DISTINCT j (lanes own disjoint j sets, self excluded)
    // are <= v  =>  the 32 smallest (d16,j) keys all have d16 <= v.
    uint32_t v = 0;
    #pragma unroll
    for (int b = 15; b >= 0; --b) {
        uint32_t t = v | (1u << b);
        int nl = (int)__popcll(__ballot(m16 < t));
        if (nl < KK) v = t;
    }

    // ---- compaction: ONE pass, slots via per-wave LDS atomic. Slot ORDER
    //      is irrelevant (rank-select orders by key), so no scan/staging.
    //      Key trick: k=(d16<<16)|j compared vs vk=(v<<16)|0xffff avoids
    //      unpacking d16 (k<=vk  <=>  d16<=v, since j<=0xfff). ----
    uint32_t cnt;
    {
        const ushort* dbf = sm.uw[wid].dbf;
        const uint32_t vk  = (v << 16) | 0xffffu;
        const uint32_t jb0 = 4*lane;
        #pragma unroll 4
        for (int g = 0; g < 16; ++g) {
            uint2 w = *((const uint2*)&dbf[g*256 + 4*lane]);
            uint32_t jb = jb0 + g*256;
            uint32_t k0 = (w.x << 16) | jb;
            uint32_t k1 = (w.x & 0xffff0000u) | (jb + 1);
            uint32_t k2 = (w.y << 16) | (jb + 2);
            uint32_t k3 = (w.y & 0xffff0000u) | (jb + 3);
            if (k0 <= vk) { uint32_t s = atomicAdd(&sm.ccnt[wid], 1u);
                            if (s < CAP) sm.cand[wid][s] = k0; }
            if (k1 <= vk) { uint32_t s = atomicAdd(&sm.ccnt[wid], 1u);
                            if (s < CAP) sm.cand[wid][s] = k1; }
            if (k2 <= vk) { uint32_t s = atomicAdd(&sm.ccnt[wid], 1u);
                            if (s < CAP) sm.cand[wid][s] = k2; }
            if (k3 <= vk) { uint32_t s = atomicAdd(&sm.ccnt[wid], 1u);
                            if (s < CAP) sm.cand[wid][s] = k3; }
        }
        cnt = sm.ccnt[wid];   // this wave's atomics precede in DS program order
    }
    const int cntv = (int)cnt;

    if (cntv <= CAP) {
        // sentinel-fill cand[cntv..CAP): keys 0xFFFFFFFF exceed any real key
        // ((d16<<16)|j <= 0xffff0fff), so the rank loop runs block-wise with
        // NO per-element bounds checks; trip count is dynamic (typ. 3-5).
        for (int idx = cntv + lane; idx < CAP; idx += 64)
            sm.cand[wid][idx] = 0xffffffffu;

        const int nb = (cntv + 15) >> 4;      // 16-key blocks to scan
        // ---- rank-select: lane ranks cand[lane] and cand[64+lane] ----
        #pragma unroll
        for (int h = 0; h < 2; ++h) {
            int idx = h*64 + lane;
            if (idx < cntv) {
                uint32_t km = sm.cand[wid][idx];
                int rank = 0;
                for (int q = 0; q < nb; ++q) {
                    const uint4* cp = (const uint4*)&sm.cand[wid][q*16];
                    uint4 u0 = cp[0];
                    uint4 u1 = cp[1];
                    uint4 u2 = cp[2];
                    uint4 u3 = cp[3];
                    rank += (u0.x < km) ? 1 : 0;
                    rank += (u0.y < km) ? 1 : 0;
                    rank += (u0.z < km) ? 1 : 0;
                    rank += (u0.w < km) ? 1 : 0;
                    rank += (u1.x < km) ? 1 : 0;
                    rank += (u1.y < km) ? 1 : 0;
                    rank += (u1.z < km) ? 1 : 0;
                    rank += (u1.w < km) ? 1 : 0;
                    rank += (u2.x < km) ? 1 : 0;
                    rank += (u2.y < km) ? 1 : 0;
                    rank += (u2.z < km) ? 1 : 0;
                    rank += (u2.w < km) ? 1 : 0;
                    rank += (u3.x < km) ? 1 : 0;
                    rank += (u3.y < km) ? 1 : 0;
                    rank += (u3.z < km) ? 1 : 0;
                    rank += (u3.w < km) ? 1 : 0;
                }
                if (rank < KK) sm.recvs[wid][rank] = (int)(km & 0xFFFFu);
            }
        }
    } else {
        // ---- cold fallback (overflow; ~never): exact wave-local argmin x32,
        //      per-lane 64-bit exclusion mask for its own j's (recompute) ----
        unsigned long long locmask = 0ull;
        if (selfLane)                          // exclude self
            locmask |= 1ull << ((sgrp << 2) | selfc);
        for (int it = 0; it < KK; ++it) {
            unsigned long long best = ~0ull;
            for (int g = 0; g < 16; ++g) {
                float d[4];
                dist4s(p4, g, lane, px, py, pz, d);
                #pragma unroll
                for (int c = 0; c < 4; ++c) {
                    bool dead = ((locmask >> (g*4 + c)) & 1ull) != 0ull;
                    unsigned long long key = dead ? ~0ull
                        : ((((unsigned long long)__float_as_uint(d[c])) << 12)
                           | (unsigned)(g*256 + 4*lane + c));
                    best = best < key ? best : key;
                }
            }
            #pragma unroll
            for (int m = 32; m >= 1; m >>= 1) {
                unsigned long long o = __shfl_xor(best, m, 64);
                best = best < o ? best : o;
            }
            int j = (int)(best & 0xfffull);
            if (lane == 0) sm.recvs[wid][it] = j;
            if (((j >> 2) & 63) == lane)
                locmask |= 1ull << ((j >> 8) * 4 + (j & 3));
        }
    }

    // ---- edge gather: lane e < 32 holds neighbor e's geometry ----
    float cdx = 0.f, cdy = 0.f, cdz = 0.f;
    if (lane < KK) {
        int r = sm.recvs[wid][lane];
        cdx = px - pos[3*r];
        cdy = py - pos[3*r+1];
        cdz = pz - pos[3*r+2];
        float rad = __fadd_rn(__fadd_rn(__fmul_rn(cdx,cdx), __fmul_rn(cdy,cdy)),
                              __fmul_rn(cdz,cdz));
        sm.rads[wid][lane] = rad;
    }

    // ---- layer 1: all 32 edges of this node; lane = ch*4 + epr ----
    // h1 overwrites dbf (same union region) — all dbf reads completed above in
    // this wave's program order.
    {
        const int ch = lane >> 2, epr = lane & 3;
        float4 wA = ((const float4*)W1)[ch*4    ];
        float4 wB = ((const float4*)W1)[ch*4 + 1];
        float4 wC = ((const float4*)W1)[ch*4 + 2];
        float4 wD = ((const float4*)W1)[ch*4 + 3];
        float4 bA = ((const float4*)b1)[ch*2], bB = ((const float4*)b1)[ch*2 + 1];
        float4 gA = ((const float4*)g1)[ch*2], gB = ((const float4*)g1)[ch*2 + 1];
        float av[8] = {wA.x, wA.z, wB.x, wB.z, wC.x, wC.z, wD.x, wD.z};
        float cv[8] = {ts*wA.y + bA.x, ts*wA.w + bA.y, ts*wB.y + bA.z, ts*wB.w + bA.w,
                       ts*wC.y + bB.x, ts*wC.w + bB.y, ts*wD.y + bB.z, ts*wD.w + bB.w};
        float gv[8] = {gA.x, gA.y, gA.z, gA.w, gB.x, gB.y, gB.z, gB.w};
        uint4* h1q = (uint4*)&sm.uw[wid].h1[0];
        #pragma unroll
        for (int g = 0; g < 8; ++g) {
            int E = 4*g + epr;                    // 0..31
            float rad = sm.rads[wid][E];
            float sqv = rad*rad*A2 + 2.0f*rad*AC + C2;
            float rn  = fastrsq(sqv * (1.0f/HID) + 1e-5f);
            uint32_t pk[4];
            #pragma unroll
            for (int p = 0; p < 4; ++p) {
                float va = siluf((rad*av[2*p]   + cv[2*p])   * rn * gv[2*p]);
                float vb = siluf((rad*av[2*p+1] + cv[2*p+1]) * rn * gv[2*p+1]);
                pk[p] = pk2bf(va, vb);
            }
            h1q[E*16 + (ch ^ (E & 15))] = uint4{pk[0], pk[1], pk[2], pk[3]};
        }
    }
    // no barrier: h1[wid] written and read only by this wave (DS program order)

    // ---- epilogue constants: n = nt*16 + l15 (shared by both m-tile passes) ----
    float g2v[8], w3v[8], b2v[8];
    #pragma unroll
    for (int nt = 0; nt < 8; ++nt) {
        int n = nt*16 + l15;
        g2v[nt] = g2[n]; w3v[nt] = W3[n]; b2v[nt] = b2[n];
    }

    // ---- layer 2 + epilogue: two m-tile passes (16 edges each), all 8 n-tiles ----
    const bf16x8* h1v = (const bf16x8*)&sm.uw[wid].h1[0];
    #pragma unroll
    for (int mt = 0; mt < 2; ++mt) {
        f32x4 acc[8];
        #pragma unroll
        for (int nt = 0; nt < 8; ++nt) acc[nt] = f32x4{0.f, 0.f, 0.f, 0.f};
        const int m = mt*16 + l15;
        if constexpr (WS) {
            const bf16x8* bv = (const bf16x8*)w2b;
            #pragma unroll
            for (int kk = 0; kk < 4; ++kk) {
                bf16x8 af = h1v[m*16 + ((kk*4 + lq) ^ l15)];
                #pragma unroll
                for (int nt = 0; nt < 8; ++nt)
                    acc[nt] = __builtin_amdgcn_mfma_f32_16x16x32_bf16(
                                  af, bv[(nt*4 + kk)*64 + lane], acc[nt], 0, 0, 0);
            }
        } else {
            const bf16x8* w2v = (const bf16x8*)sm.w2l;    // [128][16 chunks]
            #pragma unroll
            for (int kk = 0; kk < 4; ++kk) {
                const int q = (kk*4 + lq) ^ l15;
                bf16x8 af = h1v[m*16 + q];
                #pragma unroll
                for (int nt = 0; nt < 8; ++nt)
                    acc[nt] = __builtin_amdgcn_mfma_f32_16x16x32_bf16(
                                  af, w2v[(nt*16 + l15)*16 + q], acc[nt], 0, 0, 0);
            }
        }

        // RMS over all 128 neurons: in-lane sum over 8 nt + DPP row-16 sum
        float ss[4];
        #pragma unroll
        for (int r = 0; r < 4; ++r) {
            float t = 0.f;
            #pragma unroll
            for (int nt = 0; nt < 8; ++nt) {
                float zz = acc[nt][r] + b2v[nt];
                acc[nt][r] = zz;
                t += zz*zz;
            }
            ss[r] = rowsum16(t);
        }
        float sp[4];
        #pragma unroll
        for (int r = 0; r < 4; ++r) {
            float rn = fastrsq(ss[r] * (1.0f/HID) + 1e-5f);
            float t = 0.f;
            #pragma unroll
            for (int nt = 0; nt < 8; ++nt)
                t += siluf(acc[nt][r] * rn * g2v[nt]) * w3v[nt];
            sp[r] = rowsum16(t);
        }
        if (l15 == 0) {
            #pragma unroll
            for (int r = 0; r < 4; ++r)
                sm.sedge[wid][mt*16 + lq*4 + r] = sp[r] + b3s;
        }
    }

    // ---- final: sum 32 edge messages (lane e holds cd of edge e) ----
    float mx = 0.f, my = 0.f, mz = 0.f;
    if (lane < KK) {
        float s = sm.sedge[wid][lane];
        mx = cdx * s; my = cdy * s; mz = cdz * s;
    }
    mx = wsum64(mx);
    my = wsum64(my);
    mz = wsum64(mz);
    if (lane == 0) {
        out[3*i    ] = px + mx * (1.0f/KK);
        out[3*i + 1] = py + my * (1.0f/KK);
        out[3*i + 2] = pz + mz * (1.0f/KK);
    }
}

extern "C" void kernel_launch(void* const* d_in, const int* in_sizes, int n_in,
                              void* d_out, int out_size, void* d_ws, size_t ws_size,
                              hipStream_t stream) {
    (void)in_sizes; (void)n_in; (void)out_size;
    const float* pos = (const float*)d_in[0];
    const float* t   = (const float*)d_in[1];
    const float* W1  = (const float*)d_in[2];
    const float* b1  = (const float*)d_in[3];
    const float* g1  = (const float*)d_in[4];
    const float* W2  = (const float*)d_in[5];
    const float* b2  = (const float*)d_in[6];
    const float* g2  = (const float*)d_in[7];
    const float* W3  = (const float*)d_in[8];
    const float* b3  = (const float*)d_in[9];
    float* out = (float*)d_out;

    if (d_ws != nullptr && ws_size >= 32768) {
        prepack_w2<<<8, 256, 0, stream>>>(W2, (uint4*)d_ws);
        egnn_main<true><<<GRID, BLK, 0, stream>>>(
            pos, t, W1, b1, g1, W2, b2, g2, W3, b3, (const uint4*)d_ws, out);
    } else {
        egnn_main<false><<<GRID, BLK, 0, stream>>>(
            pos, t, W1, b1, g1, W2, b2, g2, W3, b3, nullptr, out);
    }
}

// Round 9
// 99.302 us; speedup vs baseline: 1.1784x; 1.0636x over previous
//
#include <hip/hip_runtime.h>
#include <stdint.h>

#define NN   4096
#define KK   32
#define HID  128
#define BLK  256
#define NPB  2                 // nodes per block
#define GRID (NN / NPB)        // 2048 blocks
#define CAP  128

typedef unsigned short bf16_t;
typedef __attribute__((ext_vector_type(8))) short bf16x8;
typedef __attribute__((ext_vector_type(4))) float f32x4;
typedef __attribute__((ext_vector_type(2))) float f32x2;

#define FINF __uint_as_float(0x7f800000u)

__device__ __forceinline__ uint32_t pk2bf(float lo, float hi) {
    uint32_t r;
    asm("v_cvt_pk_bf16_f32 %0, %1, %2" : "=v"(r) : "v"(lo), "v"(hi));
    return r;
}
__device__ __forceinline__ float fastrcp(float x) {
    float r; asm("v_rcp_f32 %0, %1" : "=v"(r) : "v"(x)); return r;
}
__device__ __forceinline__ float fastrsq(float x) {
    float r; asm("v_rsq_f32 %0, %1" : "=v"(r) : "v"(x)); return r;
}
__device__ __forceinline__ float siluf(float x) {
    return x * fastrcp(1.0f + __expf(-x));
}
__device__ __forceinline__ f32x2 pk_add(f32x2 a, f32x2 b) {
    f32x2 r; asm("v_pk_add_f32 %0, %1, %2" : "=v"(r) : "v"(a), "v"(b)); return r;
}
__device__ __forceinline__ f32x2 pk_sq(f32x2 a) {
    f32x2 r; asm("v_pk_mul_f32 %0, %1, %1" : "=v"(r) : "v"(a)); return r;
}

// DPP cross-lane sums (VALU pipe, no LDS)
template<int CTRL>
__device__ __forceinline__ float rsum_step(float x) {
    return x + __int_as_float(__builtin_amdgcn_update_dpp(
        0, __float_as_int(x), CTRL, 0xF, 0xF, true));
}
__device__ __forceinline__ float rowsum16(float x) {
    x = rsum_step<0xB1>(x);
    x = rsum_step<0x4E>(x);
    x = rsum_step<0x124>(x);
    x = rsum_step<0x128>(x);
    return x;
}
__device__ __forceinline__ float wsum64(float x) {
    x = rowsum16(x);
    x += __shfl_xor(x, 16, 64);
    x += __shfl_xor(x, 32, 64);
    return x;
}

// exact scalar distance (cold fallback only) — reference IEEE chain
__device__ __forceinline__ void dist4s(const float4* __restrict__ p4, int g, int lane,
                                       float px, float py, float pz, float d[4]) {
    float4 f0 = p4[g*192 + 3*lane];
    float4 f1 = p4[g*192 + 3*lane + 1];
    float4 f2 = p4[g*192 + 3*lane + 2];
    float jx[4] = {f0.x, f0.w, f1.z, f2.y};
    float jy[4] = {f0.y, f1.x, f1.w, f2.z};
    float jz[4] = {f0.z, f1.y, f2.x, f2.w};
    #pragma unroll
    for (int c = 0; c < 4; ++c) {
        float dx = px - jx[c], dy = py - jy[c], dz = pz - jz[c];
        d[c] = __fadd_rn(__fadd_rn(__fmul_rn(dx,dx), __fmul_rn(dy,dy)),
                         __fmul_rn(dz,dz));
    }
}

// ---- prepack: W2 fp32 -> bf16 in MFMA B-fragment order (frag f = NT*4+kk) ----
__global__ __launch_bounds__(256) void prepack_w2(
    const float* __restrict__ W2, uint4* __restrict__ w2b)
{
    int c  = blockIdx.x * 256 + threadIdx.x;
    int f  = c >> 6, ln = c & 63;
    int NT = f >> 2, kk = f & 3;
    int row = NT*16 + (ln & 15);
    int k0  = kk*32 + (ln >> 4) * 8;
    const float* s = W2 + row * HID + k0;
    float4 lo = *(const float4*)s;
    float4 hi = *(const float4*)(s + 4);
    uint4 pk;
    pk.x = pk2bf(lo.x, lo.y);
    pk.y = pk2bf(lo.z, lo.w);
    pk.z = pk2bf(hi.x, hi.y);
    pk.w = pk2bf(hi.z, hi.w);
    w2b[c] = pk;
}

template<bool WS>
struct __align__(16) Sm {
    ushort   h1[NPB][KK * HID];         // 16 KB: MFMA A-operand per node
    uint32_t cand[NPB][CAP];            // 1 KB
    uint32_t ccnt[NPB];                 // shared candidate counter per node
    ushort   smin[NPB][2][64];          // per-lane half-mins exchange
    float    rads[NPB][KK];
    float    sedge[NPB][KK];
    int      recvs[NPB][KK];
    float    partial[NPB][2][4];        // final message partials per wave
    uint32_t w2l[WS ? 4 : HID * 64];    // W2 staging only in no-workspace path
};

template<bool WS>
__global__ __launch_bounds__(BLK) void egnn_main(
    const float* __restrict__ pos, const float* __restrict__ tptr,
    const float* __restrict__ W1,  const float* __restrict__ b1,
    const float* __restrict__ g1,  const float* __restrict__ W2,
    const float* __restrict__ b2,  const float* __restrict__ g2,
    const float* __restrict__ W3,  const float* __restrict__ b3,
    const uint4* __restrict__ w2b, float* __restrict__ out)
{
    __shared__ Sm<WS> sm;
    const int tid  = threadIdx.x;
    const int lane = tid & 63;
    const int wid  = tid >> 6;                  // 0..3
    const int p    = wid >> 1;                  // node slot in block (0..1)
    const int sub  = wid & 1;                   // half-wave of the pair
    const int i    = blockIdx.x * NPB + p;      // node handled by this pair
    const int l15  = lane & 15, lq = lane >> 4;

    if (tid < NPB) sm.ccnt[tid] = 0;            // visible after B1

    const float ts  = tptr[0];
    const float b3s = b3[0];

    // closed-form RMS coefficients (wave-reduced -> lane-uniform)
    float A2, AC, C2;
    {
        const float4 w1v = ((const float4*)W1)[lane];
        const float2 b1v = ((const float2*)b1)[lane];
        float t0 = ts * w1v.y + b1v.x;
        float t1 = ts * w1v.w + b1v.y;
        A2 = wsum64(w1v.x*w1v.x + w1v.z*w1v.z);
        AC = wsum64(w1v.x*t0    + w1v.z*t1);
        C2 = wsum64(t0*t0       + t1*t1);
    }

    if constexpr (!WS) {
        for (int idx = tid; idx < HID * 16; idx += BLK) {
            int row = idx >> 4, c = idx & 15;
            const float* src = W2 + row * HID + c * 8;
            float4 lo = *(const float4*)src;
            float4 hi = *(const float4*)(src + 4);
            uint4 pk;
            pk.x = pk2bf(lo.x, lo.y);
            pk.y = pk2bf(lo.z, lo.w);
            pk.z = pk2bf(hi.x, hi.y);
            pk.w = pk2bf(hi.z, hi.w);
            *((uint4*)&sm.w2l[row * 64 + 4 * (c ^ (row & 15))]) = pk;
        }
        // made visible by B1 below (before any w2l read)
    }

    const float px = pos[3*i], py = pos[3*i+1], pz = pos[3*i+2];
    const float4* p4 = (const float4*)pos;
    const f32x2 nPxy = {-px, -py}, nPzx = {-pz, -px}, nPyz = {-py, -pz};

    const int  sgrp     = i >> 8;
    const bool selfLane = ((i >> 2) & 63) == lane;
    const int  selfc    = i & 3;

    // ---- phase A: own-half distances (8 of 16 groups) into REGISTERS ----
    uint32_t dlo[8], dhi[8];
    float mind = FINF;
    #pragma unroll
    for (int gg = 0; gg < 8; ++gg) {
        const int g = sub*8 + gg;
        float4 f0 = p4[g*192 + 3*lane];   // x0 y0 z0 x1
        float4 f1 = p4[g*192 + 3*lane+1]; // y1 z1 x2 y2
        float4 f2 = p4[g*192 + 3*lane+2]; // z2 x3 y3 z3
        f32x2 S0 = pk_sq(pk_add(f32x2{f0.x, f0.y}, nPxy));
        f32x2 S1 = pk_sq(pk_add(f32x2{f0.z, f0.w}, nPzx));
        f32x2 S2 = pk_sq(pk_add(f32x2{f1.x, f1.y}, nPyz));
        f32x2 S3 = pk_sq(pk_add(f32x2{f1.z, f1.w}, nPxy));
        f32x2 S4 = pk_sq(pk_add(f32x2{f2.x, f2.y}, nPzx));
        f32x2 S5 = pk_sq(pk_add(f32x2{f2.z, f2.w}, nPyz));
        float d0 = S0.x + S0.y + S1.x;
        float d1 = S1.y + S2.x + S2.y;
        float d2 = S3.x + S3.y + S4.x;
        float d3 = S4.y + S5.x + S5.y;
        if (g == sgrp && selfLane) {
            d0 = (selfc == 0) ? FINF : d0;
            d1 = (selfc == 1) ? FINF : d1;
            d2 = (selfc == 2) ? FINF : d2;
            d3 = (selfc == 3) ? FINF : d3;
        }
        dlo[gg] = __builtin_amdgcn_perm(__float_as_uint(d1),
                                        __float_as_uint(d0), 0x07060302u);
        dhi[gg] = __builtin_amdgcn_perm(__float_as_uint(d3),
                                        __float_as_uint(d2), 0x07060302u);
        mind = fminf(fminf(fminf(mind, d0), fminf(d1, d2)), d3);
    }
    // exchange per-lane half-mins across the pair
    const uint32_t m16own = __float_as_uint(mind) >> 16;
    sm.smin[p][sub][lane] = (ushort)m16own;
    __syncthreads();                                        // B1
    uint32_t m16;
    {
        uint32_t o = (uint32_t)sm.smin[p][sub ^ 1][lane];
        m16 = m16own < o ? m16own : o;                      // full 64-j lane min
    }

    // ---- v = 32nd smallest combined sample-min (radix; duplicated per wave) ----
    uint32_t v = 0;
    #pragma unroll
    for (int b = 15; b >= 0; --b) {
        uint32_t t = v | (1u << b);
        int nl = (int)__popcll(__ballot(m16 < t));
        if (nl < KK) v = t;
    }

    // ---- phase B: compaction straight from registers (own half) ----
    {
        const uint32_t vk = (v << 16) | 0xffffu;
        #pragma unroll
        for (int gg = 0; gg < 8; ++gg) {
            uint32_t jb = (uint32_t)((sub*8 + gg)*256 + 4*lane);
            uint32_t k0 = (dlo[gg] << 16) | jb;
            uint32_t k1 = (dlo[gg] & 0xffff0000u) | (jb + 1);
            uint32_t k2 = (dhi[gg] << 16) | (jb + 2);
            uint32_t k3 = (dhi[gg] & 0xffff0000u) | (jb + 3);
            if (k0 <= vk) { uint32_t s = atomicAdd(&sm.ccnt[p], 1u);
                            if (s < CAP) sm.cand[p][s] = k0; }
            if (k1 <= vk) { uint32_t s = atomicAdd(&sm.ccnt[p], 1u);
                            if (s < CAP) sm.cand[p][s] = k1; }
            if (k2 <= vk) { uint32_t s = atomicAdd(&sm.ccnt[p], 1u);
                            if (s < CAP) sm.cand[p][s] = k2; }
            if (k3 <= vk) { uint32_t s = atomicAdd(&sm.ccnt[p], 1u);
                            if (s < CAP) sm.cand[p][s] = k3; }
        }
    }
    __syncthreads();                                        // B2
    const int cntv = (int)sm.ccnt[p];

    if (cntv <= CAP) {
        // both waves redundantly sentinel-fill the whole tail (identical
        // values -> benign race; avoids an extra barrier)
        for (int idx = cntv + lane; idx < CAP; idx += 64)
            sm.cand[p][idx] = 0xffffffffu;

        const int nb = (cntv + 15) >> 4;
        // rank-select: wave sub ranks idx = sub*64 + lane (128 idx across pair)
        const int idx = sub*64 + lane;
        if (idx < cntv) {
            uint32_t km = sm.cand[p][idx];
            int rank = 0;
            for (int q = 0; q < nb; ++q) {
                const uint4* cp = (const uint4*)&sm.cand[p][q*16];
                uint4 u0 = cp[0];
                uint4 u1 = cp[1];
                uint4 u2 = cp[2];
                uint4 u3 = cp[3];
                rank += (u0.x < km) ? 1 : 0;
                rank += (u0.y < km) ? 1 : 0;
                rank += (u0.z < km) ? 1 : 0;
                rank += (u0.w < km) ? 1 : 0;
                rank += (u1.x < km) ? 1 : 0;
                rank += (u1.y < km) ? 1 : 0;
                rank += (u1.z < km) ? 1 : 0;
                rank += (u1.w < km) ? 1 : 0;
                rank += (u2.x < km) ? 1 : 0;
                rank += (u2.y < km) ? 1 : 0;
                rank += (u2.z < km) ? 1 : 0;
                rank += (u2.w < km) ? 1 : 0;
                rank += (u3.x < km) ? 1 : 0;
                rank += (u3.y < km) ? 1 : 0;
                rank += (u3.z < km) ? 1 : 0;
                rank += (u3.w < km) ? 1 : 0;
            }
            if (rank < KK) sm.recvs[p][rank] = (int)(km & 0xFFFFu);
        }
    } else if (sub == 0) {
        // cold fallback (~never): single wave of the pair, full recompute
        unsigned long long locmask = 0ull;
        if (selfLane)
            locmask |= 1ull << ((sgrp << 2) | selfc);
        for (int it = 0; it < KK; ++it) {
            unsigned long long best = ~0ull;
            for (int g = 0; g < 16; ++g) {
                float d[4];
                dist4s(p4, g, lane, px, py, pz, d);
                #pragma unroll
                for (int c = 0; c < 4; ++c) {
                    bool dead = ((locmask >> (g*4 + c)) & 1ull) != 0ull;
                    unsigned long long key = dead ? ~0ull
                        : ((((unsigned long long)__float_as_uint(d[c])) << 12)
                           | (unsigned)(g*256 + 4*lane + c));
                    best = best < key ? best : key;
                }
            }
            #pragma unroll
            for (int m = 32; m >= 1; m >>= 1) {
                unsigned long long o = __shfl_xor(best, m, 64);
                best = best < o ? best : o;
            }
            int j = (int)(best & 0xfffull);
            if (lane == 0) sm.recvs[p][it] = j;
            if (((j >> 2) & 63) == lane)
                locmask |= 1ull << ((j >> 8) * 4 + (j & 3));
        }
    }
    __syncthreads();                                        // B3

    // ---- phase D: gather own 16 edges (lane e<16 -> edge sub*16+e) ----
    float cdx = 0.f, cdy = 0.f, cdz = 0.f;
    if (lane < 16) {
        int e = sub*16 + lane;
        int r = sm.recvs[p][e];
        cdx = px - pos[3*r];
        cdy = py - pos[3*r+1];
        cdz = pz - pos[3*r+2];
        float rad = __fadd_rn(__fadd_rn(__fmul_rn(cdx,cdx), __fmul_rn(cdy,cdy)),
                              __fmul_rn(cdz,cdz));
        sm.rads[p][e] = rad;
    }

    // ---- phase E: layer 1 for own 16 edges; lane = ch*4 + epr ----
    // own h1 rows [sub*16, sub*16+16) — written and later read by THIS wave
    // only (DS program order), so no barrier before MFMA.
    {
        const int ch = lane >> 2, epr = lane & 3;
        float4 wA = ((const float4*)W1)[ch*4    ];
        float4 wB = ((const float4*)W1)[ch*4 + 1];
        float4 wC = ((const float4*)W1)[ch*4 + 2];
        float4 wD = ((const float4*)W1)[ch*4 + 3];
        float4 bA = ((const float4*)b1)[ch*2], bB = ((const float4*)b1)[ch*2 + 1];
        float4 gA = ((const float4*)g1)[ch*2], gB = ((const float4*)g1)[ch*2 + 1];
        float av[8] = {wA.x, wA.z, wB.x, wB.z, wC.x, wC.z, wD.x, wD.z};
        float cv[8] = {ts*wA.y + bA.x, ts*wA.w + bA.y, ts*wB.y + bA.z, ts*wB.w + bA.w,
                       ts*wC.y + bB.x, ts*wC.w + bB.y, ts*wD.y + bB.z, ts*wD.w + bB.w};
        float gv[8] = {gA.x, gA.y, gA.z, gA.w, gB.x, gB.y, gB.z, gB.w};
        uint4* h1q = (uint4*)&sm.h1[p][0];
        #pragma unroll
        for (int g2i = 0; g2i < 4; ++g2i) {
            int E = sub*16 + 4*g2i + epr;         // own 16 edges
            float rad = sm.rads[p][E];
            float sqv = rad*rad*A2 + 2.0f*rad*AC + C2;
            float rn  = fastrsq(sqv * (1.0f/HID) + 1e-5f);
            uint32_t pk[4];
            #pragma unroll
            for (int pp = 0; pp < 4; ++pp) {
                float va = siluf((rad*av[2*pp]   + cv[2*pp])   * rn * gv[2*pp]);
                float vb = siluf((rad*av[2*pp+1] + cv[2*pp+1]) * rn * gv[2*pp+1]);
                pk[pp] = pk2bf(va, vb);
            }
            h1q[E*16 + (ch ^ (E & 15))] = uint4{pk[0], pk[1], pk[2], pk[3]};
        }
    }

    // ---- epilogue constants ----
    float g2v[8], w3v[8], b2v[8];
    #pragma unroll
    for (int nt = 0; nt < 8; ++nt) {
        int n = nt*16 + l15;
        g2v[nt] = g2[n]; w3v[nt] = W3[n]; b2v[nt] = b2[n];
    }

    // ---- phase F: layer 2 + epilogue, SINGLE m-tile (mt = sub) ----
    const bf16x8* h1v = (const bf16x8*)&sm.h1[p][0];
    {
        f32x4 acc[8];
        #pragma unroll
        for (int nt = 0; nt < 8; ++nt) acc[nt] = f32x4{0.f, 0.f, 0.f, 0.f};
        const int m = sub*16 + l15;
        if constexpr (WS) {
            const bf16x8* bv = (const bf16x8*)w2b;
            #pragma unroll
            for (int kk = 0; kk < 4; ++kk) {
                bf16x8 af = h1v[m*16 + ((kk*4 + lq) ^ l15)];
                #pragma unroll
                for (int nt = 0; nt < 8; ++nt)
                    acc[nt] = __builtin_amdgcn_mfma_f32_16x16x32_bf16(
                                  af, bv[(nt*4 + kk)*64 + lane], acc[nt], 0, 0, 0);
            }
        } else {
            const bf16x8* w2v = (const bf16x8*)sm.w2l;
            #pragma unroll
            for (int kk = 0; kk < 4; ++kk) {
                const int q = (kk*4 + lq) ^ l15;
                bf16x8 af = h1v[m*16 + q];
                #pragma unroll
                for (int nt = 0; nt < 8; ++nt)
                    acc[nt] = __builtin_amdgcn_mfma_f32_16x16x32_bf16(
                                  af, w2v[(nt*16 + l15)*16 + q], acc[nt], 0, 0, 0);
            }
        }

        float ss[4];
        #pragma unroll
        for (int r = 0; r < 4; ++r) {
            float t = 0.f;
            #pragma unroll
            for (int nt = 0; nt < 8; ++nt) {
                float zz = acc[nt][r] + b2v[nt];
                acc[nt][r] = zz;
                t += zz*zz;
            }
            ss[r] = rowsum16(t);
        }
        float sp[4];
        #pragma unroll
        for (int r = 0; r < 4; ++r) {
            float rn = fastrsq(ss[r] * (1.0f/HID) + 1e-5f);
            float t = 0.f;
            #pragma unroll
            for (int nt = 0; nt < 8; ++nt)
                t += siluf(acc[nt][r] * rn * g2v[nt]) * w3v[nt];
            sp[r] = rowsum16(t);
        }
        if (l15 == 0) {
            #pragma unroll
            for (int r = 0; r < 4; ++r)
                sm.sedge[p][sub*16 + lq*4 + r] = sp[r] + b3s;
        }
    }

    // ---- phase G: own 16 edge messages, then pair combine ----
    float mx = 0.f, my = 0.f, mz = 0.f;
    if (lane < 16) {
        float s = sm.sedge[p][sub*16 + lane];   // own half, own-wave writes
        mx = cdx * s; my = cdy * s; mz = cdz * s;
    }
    mx = wsum64(mx);
    my = wsum64(my);
    mz = wsum64(mz);
    if (lane == 0) {
        sm.partial[p][sub][0] = mx;
        sm.partial[p][sub][1] = my;
        sm.partial[p][sub][2] = mz;
    }
    __syncthreads();                                        // B4
    if (sub == 0 && lane == 0) {
        float fx = sm.partial[p][0][0] + sm.partial[p][1][0];
        float fy = sm.partial[p][0][1] + sm.partial[p][1][1];
        float fz = sm.partial[p][0][2] + sm.partial[p][1][2];
        out[3*i    ] = px + fx * (1.0f/KK);
        out[3*i + 1] = py + fy * (1.0f/KK);
        out[3*i + 2] = pz + fz * (1.0f/KK);
    }
}

extern "C" void kernel_launch(void* const* d_in, const int* in_sizes, int n_in,
                              void* d_out, int out_size, void* d_ws, size_t ws_size,
                              hipStream_t stream) {
    (void)in_sizes; (void)n_in; (void)out_size;
    const float* pos = (const float*)d_in[0];
    const float* t   = (const float*)d_in[1];
    const float* W1  = (const float*)d_in[2];
    const float* b1  = (const float*)d_in[3];
    const float* g1  = (const float*)d_in[4];
    const float* W2  = (const float*)d_in[5];
    const float* b2  = (const float*)d_in[6];
    const float* g2  = (const float*)d_in[7];
    const float* W3  = (const float*)d_in[8];
    const float* b3  = (const float*)d_in[9];
    float* out = (float*)d_out;

    if (d_ws != nullptr && ws_size >= 32768) {
        prepack_w2<<<8, 256, 0, stream>>>(W2, (uint4*)d_ws);
        egnn_main<true><<<GRID, BLK, 0, stream>>>(
            pos, t, W1, b1, g1, W2, b2, g2, W3, b3, (const uint4*)d_ws, out);
    } else {
        egnn_main<false><<<GRID, BLK, 0, stream>>>(
            pos, t, W1, b1, g1, W2, b2, g2, W3, b3, nullptr, out);
    }
}